// Round 13
// baseline (589.659 us; speedup 1.0000x reference)
//
#include <hip/hip_runtime.h>
#include <hip/hip_bf16.h>
#include <stdint.h>

#define NNODES 72000
#define NBO 2000
#define NBU 20000
#define NBI 50000
#define NEDGE 1152000
#define VOCAB 50000
#define TSEQ 20
#define BSZ 1024
#define KNEG 4
#define NSB 71     // scan blocks: 71*1024 >= 72000
#define NSLOT (2 * BSZ + KNEG * BSZ)   // 6144 scored slots: user | pos | neg
#define EB_ELEM ((VOCAB + 1) * 32)     // 1,600,032 packed words
#define EB_BLKS ((EB_ELEM + 255) / 256)
#define DEG_BLKS ((NEDGE + 255) / 256)

typedef __attribute__((ext_vector_type(8))) short bf16x8;
typedef __attribute__((ext_vector_type(4))) float f32x4;

__device__ __forceinline__ float rcp_fast(float x){ return __builtin_amdgcn_rcpf(x); }
__device__ __forceinline__ float sigmoidf_(float x){ return rcp_fast(1.f + __expf(-x)); }
__device__ __forceinline__ float tanhf_(float x){
    float xx = fminf(fmaxf(x, -15.f), 15.f);
    float e = __expf(-2.f * xx);
    return (1.f - e) * rcp_fast(1.f + e);
}
__device__ __forceinline__ uint32_t f2bf_rne(float f){
    uint32_t u = __float_as_uint(f);
    return (u + 0x7fffu + ((u >> 16) & 1u)) >> 16;
}
// HW packed convert: 2 fp32 -> 2 bf16 (v_cvt_pk_bf16_f32); memcpy = reg move
__device__ __forceinline__ uint32_t pkbf(float lo, float hi){
    __hip_bfloat162 h = __float22bfloat162_rn(make_float2(lo, hi));
    uint32_t r;
    __builtin_memcpy(&r, &h, 4);
    return r;
}
__device__ __forceinline__ float bfu_lo(uint32_t p){ return __uint_as_float(p << 16); }
__device__ __forceinline__ float bfu_hi(uint32_t p){ return __uint_as_float(p & 0xffff0000u); }

__device__ __forceinline__ f32x4 mfma16(bf16x8 a, bf16x8 b, f32x4 c){
    return __builtin_amdgcn_mfma_f32_16x16x32_bf16(a, b, c, 0, 0, 0);
}

// XOR swizzle for 128B-row LDS tiles (16B slots spread per 8-row stripe)
__device__ __forceinline__ int swz(int b){ return b ^ (((b >> 7) & 7) << 4); }
// XOR swizzle for 256B-row tiles
__device__ __forceinline__ int swzE(int b){ return b ^ (((b >> 8) & 7) << 4); }

// ---------------- MFMA GRU (r8/r9 proven: 512 thr, 2 barriers/t, no spill) ----------------

__device__ __forceinline__ void gru_layer_step(
    const char* __restrict__ xsrc, const char* __restrict__ hsrc,
    const bf16x8 (&wih)[3][2], const bf16x8 (&whh)[3][2],
    const f32x4& rb, const f32x4& zb, const f32x4& ib, const f32x4& hb,
    f32x4 (&hreg)[2], int lane, int ctb)
{
    f32x4 ar[2], az[2], ain[2], ahn[2];
    #pragma unroll
    for (int c = 0; c < 2; c++){ ar[c] = rb; az[c] = zb; ain[c] = ib; ahn[c] = hb; }
    const int lrow = (lane & 15) * 128 + (lane >> 4) * 16;
    __builtin_amdgcn_s_setprio(1);
    #pragma unroll
    for (int kf = 0; kf < 2; kf++){
        #pragma unroll
        for (int c = 0; c < 2; c++){
            int byte = (ctb + c) * 2048 + kf * 64 + lrow;
            bf16x8 bx = *(const bf16x8*)(xsrc + swz(byte));
            bf16x8 bh = *(const bf16x8*)(hsrc + swz(byte));
            ar[c]  = mfma16(wih[0][kf], bx, ar[c]);
            ar[c]  = mfma16(whh[0][kf], bh, ar[c]);
            az[c]  = mfma16(wih[1][kf], bx, az[c]);
            az[c]  = mfma16(whh[1][kf], bh, az[c]);
            ain[c] = mfma16(wih[2][kf], bx, ain[c]);
            ahn[c] = mfma16(whh[2][kf], bh, ahn[c]);
        }
    }
    __builtin_amdgcn_s_setprio(0);
    #pragma unroll
    for (int c = 0; c < 2; c++){
        #pragma unroll
        for (int r4 = 0; r4 < 4; r4++){
            float rg = sigmoidf_(ar[c][r4]);
            float zg = sigmoidf_(az[c][r4]);
            float ng = tanhf_(fmaf(rg, ahn[c][r4], ain[c][r4]));
            hreg[c][r4] = fmaf(zg, hreg[c][r4] - ng, ng);
        }
    }
}

__device__ __forceinline__ void write_h(char* __restrict__ dst,
                                        const f32x4 (&hreg)[2], int w4, int lane, int ctb)
{
    #pragma unroll
    for (int c = 0; c < 2; c++){
        uint32_t p0 = pkbf(hreg[c][0], hreg[c][1]);
        uint32_t p1 = pkbf(hreg[c][2], hreg[c][3]);
        int byte = ((ctb + c) * 16 + (lane & 15)) * 128 + w4 * 32 + (lane >> 4) * 8;
        *(uint2*)(dst + swz(byte)) = make_uint2(p0, p1);
    }
}

__global__ __launch_bounds__(512, 2)
void gru_kernel(const uint32_t* __restrict__ ebf,
                const int* __restrict__ lookup,
                const float* __restrict__ w_ih0, const float* __restrict__ w_hh0,
                const float* __restrict__ b_ih0, const float* __restrict__ b_hh0,
                const float* __restrict__ w_ih1, const float* __restrict__ w_hh1,
                const float* __restrict__ b_ih1, const float* __restrict__ b_hh1,
                const float* __restrict__ other_pos, const float* __restrict__ user_pos,
                const float* __restrict__ item_pos,
                uint32_t* __restrict__ abf)
{
    __shared__ __align__(16) char xbuf[2][8192];
    __shared__ __align__(16) char h0buf[2][8192];
    __shared__ __align__(16) char h1buf[2][8192];

    const int tid  = threadIdx.x;
    const int lane = tid & 63;
    const int wave = tid >> 6;
    const int w4   = wave & 3;
    const int ctb  = (wave >> 2) * 2;

    const float* mats[4] = { w_ih0, w_hh0, w_ih1, w_hh1 };
    bf16x8 wf[4][3][2];
    #pragma unroll
    for (int m = 0; m < 4; m++){
        #pragma unroll
        for (int g = 0; g < 3; g++){
            #pragma unroll
            for (int kf = 0; kf < 2; kf++){
                int row = (g * 4 + w4) * 16 + (lane & 15);
                int k0  = kf * 32 + (lane >> 4) * 8;
                const float* p = mats[m] + row * 64 + k0;
                float4 a = *(const float4*)p;
                float4 b = *(const float4*)(p + 4);
                bf16x8 f;
                f[0] = (short)f2bf_rne(a.x); f[1] = (short)f2bf_rne(a.y);
                f[2] = (short)f2bf_rne(a.z); f[3] = (short)f2bf_rne(a.w);
                f[4] = (short)f2bf_rne(b.x); f[5] = (short)f2bf_rne(b.y);
                f[6] = (short)f2bf_rne(b.z); f[7] = (short)f2bf_rne(b.w);
                wf[m][g][kf] = f;
            }
        }
    }

    const int bofs = w4 * 16 + (lane >> 4) * 4;
    f32x4 rb0, zb0, ib0, hb0, rb1, zb1, ib1, hb1;
    #pragma unroll
    for (int r4 = 0; r4 < 4; r4++){
        rb0[r4] = b_ih0[bofs + r4]       + b_hh0[bofs + r4];
        zb0[r4] = b_ih0[64 + bofs + r4]  + b_hh0[64 + bofs + r4];
        ib0[r4] = b_ih0[128 + bofs + r4];
        hb0[r4] = b_hh0[128 + bofs + r4];
        rb1[r4] = b_ih1[bofs + r4]       + b_hh1[bofs + r4];
        zb1[r4] = b_ih1[64 + bofs + r4]  + b_hh1[64 + bofs + r4];
        ib1[r4] = b_ih1[128 + bofs + r4];
        hb1[r4] = b_hh1[128 + bofs + r4];
    }

    {
        uint4 z4 = make_uint4(0, 0, 0, 0);
        ((uint4*)h0buf[0])[tid] = z4;
        ((uint4*)h1buf[0])[tid] = z4;
    }
    const int pnl = tid >> 3, pdg = tid & 7;
    const long nodeP = (long)blockIdx.x * 64 + pnl;
    const int sbyte = pnl * 128 + pdg * 16;
    {
        int idx = lookup[nodeP * TSEQ + 0];
        uint4 a = ((const uint4*)(ebf + (size_t)idx * 32))[pdg];
        *(uint4*)(xbuf[0] + swz(sbyte)) = a;
    }
    __syncthreads();

    f32x4 h0reg[2], h1reg[2];
    #pragma unroll
    for (int c = 0; c < 2; c++){
        #pragma unroll
        for (int r4 = 0; r4 < 4; r4++){ h0reg[c][r4] = 0.f; h1reg[c][r4] = 0.f; }
    }

    for (int t = 0; t < TSEQ; t++){
        const int p = t & 1, q = p ^ 1;
        const bool pf = (t + 1 < TSEQ);
        uint4 xa;
        if (pf){
            int idx = lookup[nodeP * TSEQ + t + 1];
            xa = ((const uint4*)(ebf + (size_t)idx * 32))[pdg];
        }
        gru_layer_step(xbuf[p], h0buf[p], wf[0], wf[1], rb0, zb0, ib0, hb0, h0reg, lane, ctb);
        write_h(h0buf[q], h0reg, w4, lane, ctb);
        __syncthreads();
        gru_layer_step(h0buf[q], h1buf[p], wf[2], wf[3], rb1, zb1, ib1, hb1, h1reg, lane, ctb);
        write_h(h1buf[q], h1reg, w4, lane, ctb);
        if (pf) *(uint4*)(xbuf[q] + swz(sbyte)) = xa;
        __syncthreads();
    }

    float* xstage = (float*)xbuf;
    #pragma unroll
    for (int c = 0; c < 2; c++){
        int nl = (ctb + c) * 16 + (lane & 15);
        int byte = nl * 256 + w4 * 64 + (lane >> 4) * 16;
        *(float4*)((char*)xstage + swzE(byte)) =
            make_float4(h1reg[c][0], h1reg[c][1], h1reg[c][2], h1reg[c][3]);
    }
    __syncthreads();
    {
        long node = nodeP;
        const float* pp; long off;
        if (node < NBO)            { pp = other_pos; off = node; }
        else if (node < NBO + NBU) { pp = user_pos;  off = node - NBO; }
        else                       { pp = item_pos;  off = node - NBO - NBU; }
        const float* pr = pp + off * 64 + pdg * 8;
        float4 pa = *(const float4*)pr;
        float4 pb = *(const float4*)(pr + 4);
        int byte = pnl * 256 + pdg * 32;
        float4 ha = *(float4*)((char*)xstage + swzE(byte));
        float4 hb2 = *(float4*)((char*)xstage + swzE(byte + 16));
        uint4 ov;
        ov.x = pkbf(pa.x + ha.x, pa.y + ha.y);
        ov.y = pkbf(pa.z + ha.z, pa.w + ha.w);
        ov.z = pkbf(pb.x + hb2.x, pb.y + hb2.y);
        ov.w = pkbf(pb.z + hb2.z, pb.w + hb2.w);
        ((uint4*)abf)[node * 8 + pdg] = ov;
    }
}

// ---------------- prep: emb2bf (blocks [0,EB_BLKS)) + deg atomics (rest) ----------------
__global__ __launch_bounds__(256)
void prep_kernel(const float* __restrict__ we, uint32_t* __restrict__ ebf,
                 const int* __restrict__ row, int* __restrict__ deg)
{
    if (blockIdx.x < EB_BLKS){
        size_t i = (size_t)blockIdx.x * 256 + threadIdx.x;
        if (i < (size_t)EB_ELEM){
            float2 v = ((const float2*)we)[i];
            ebf[i] = pkbf(v.x, v.y);
        }
    } else {
        int e = (blockIdx.x - EB_BLKS) * 256 + threadIdx.x;
        if (e < NEDGE) atomicAdd(&deg[row[e]], 1);
    }
}

// ---------------- CSR build ----------------
__global__ __launch_bounds__(1024)
void scan1_kernel(const int* __restrict__ deg, int* __restrict__ rowptr, int* __restrict__ bsum)
{
    __shared__ int wsum[16];
    const int tid = threadIdx.x, lane = tid & 63, w = tid >> 6;
    const int i = blockIdx.x * 1024 + tid;
    int v = (i < NNODES) ? deg[i] : 0;
    int s = v;
    #pragma unroll
    for (int o = 1; o < 64; o <<= 1){
        int t = __shfl_up(s, o, 64);
        if (lane >= o) s += t;
    }
    if (lane == 63) wsum[w] = s;
    __syncthreads();
    if (w == 0){
        int t = (lane < 16) ? wsum[lane] : 0;
        #pragma unroll
        for (int o = 1; o < 16; o <<= 1){
            int u = __shfl_up(t, o, 64);
            if (lane >= o) t += u;
        }
        if (lane < 16) wsum[lane] = t;
    }
    __syncthreads();
    int incl = s + ((w > 0) ? wsum[w - 1] : 0);
    if (i < NNODES) rowptr[i + 1] = incl;
    if (tid == 0) bsum[blockIdx.x] = wsum[15];
}

// scan3 with inline block-offset reduce (replaces scan2): each block sums bsum[0..bid-1]
__global__ __launch_bounds__(1024)
void scan3_kernel(const int* __restrict__ deg, int* __restrict__ rowptr,
                  const int* __restrict__ bsum, int* __restrict__ cursor)
{
    __shared__ int boff_sh;
    const int tid = threadIdx.x;
    if (tid < 64){
        int v = 0;
        for (int k = tid; k < blockIdx.x; k += 64) v += bsum[k];
        #pragma unroll
        for (int o = 32; o > 0; o >>= 1) v += __shfl_down(v, o, 64);
        if (tid == 0) boff_sh = v;
    }
    __syncthreads();
    const int i = blockIdx.x * 1024 + tid;
    if (i < NNODES){
        int r = rowptr[i + 1] + boff_sh;
        rowptr[i + 1] = r;
        cursor[i] = r - deg[i];
    }
    if (i == 0) rowptr[0] = 0;
}

__global__ __launch_bounds__(256)
void scat_kernel(const int* __restrict__ row, const int* __restrict__ col,
                 const float* __restrict__ vals, int* __restrict__ cursor,
                 int2* __restrict__ cv)
{
    int e = blockIdx.x * 256 + threadIdx.x;
    if (e < NEDGE){
        int p = atomicAdd(&cursor[row[e]], 1);
        cv[p] = make_int2(col[e], __float_as_int(vals[e]));
    }
}

// h2c[slot] = bias + sum_e A[node(slot),c] * z2[c]  -- only 6144 scored slots
__global__ __launch_bounds__(256)
void spmm128_slots(const int* __restrict__ rowptr, const int2* __restrict__ cv,
                   const uint32_t* __restrict__ zb, const float* __restrict__ b2,
                   const int* __restrict__ user, const int* __restrict__ pos_item,
                   const int* __restrict__ neg_item, float* __restrict__ h2c)
{
    const int slot = blockIdx.x * 4 + (threadIdx.x >> 6);
    const int lane = threadIdx.x & 63;
    int r;
    if (slot < BSZ)            r = NBO + user[slot];
    else if (slot < 2 * BSZ)   r = NBO + NBU + pos_item[slot - BSZ];
    else                       r = NBO + NBU + neg_item[slot - 2 * BSZ];
    const int e0 = rowptr[r], e1 = rowptr[r + 1];
    float2 acc = make_float2(b2[2 * lane], b2[2 * lane + 1]);
    int e = e0;
    for (; e + 1 < e1; e += 2){
        int2 a0 = cv[e], a1 = cv[e + 1];
        uint32_t z0 = zb[(size_t)a0.x * 64 + lane];
        uint32_t z1 = zb[(size_t)a1.x * 64 + lane];
        float v0 = __int_as_float(a0.y), v1 = __int_as_float(a1.y);
        acc.x = fmaf(v0, bfu_lo(z0), acc.x);
        acc.y = fmaf(v0, bfu_hi(z0), acc.y);
        acc.x = fmaf(v1, bfu_lo(z1), acc.x);
        acc.y = fmaf(v1, bfu_hi(z1), acc.y);
    }
    if (e < e1){
        int2 a = cv[e];
        uint32_t z0 = zb[(size_t)a.x * 64 + lane];
        float v = __int_as_float(a.y);
        acc.x = fmaf(v, bfu_lo(z0), acc.x);
        acc.y = fmaf(v, bfu_hi(z0), acc.y);
    }
    *(float2*)(h2c + (size_t)slot * 128 + 2 * lane) = acc;
}

// ---- fused spmm64 + dense: gather y1 tile -> h1 = y1@W1+b1 -> z2 = h1@W2 ----
// 64 nodes/block, 4 waves; wave w4 owns out dims [32w4, 32w4+32) in both passes.
__global__ __launch_bounds__(256, 2)
void gemm12_mfma(const int* __restrict__ rowptr, const int2* __restrict__ cv,
                 const ushort* __restrict__ xb,
                 const float* __restrict__ W1, const float* __restrict__ b1,
                 const float* __restrict__ W2,
                 uint32_t* __restrict__ h1bf, uint32_t* __restrict__ zbf)
{
    __shared__ __align__(16) char ybuf[8192];    // [64 nodes][128B bf16], swz
    __shared__ __align__(16) char hbuf[16384];   // [64 nodes][256B bf16], swzE
    const int tid = threadIdx.x, lane = tid & 63, w4 = tid >> 6;

    bf16x8 af1[2][2], af2[2][4];
    #pragma unroll
    for (int jt = 0; jt < 2; jt++){
        int jj = w4 * 32 + jt * 16 + (lane & 15);
        #pragma unroll
        for (int kf = 0; kf < 2; kf++){
            int k0 = kf * 32 + (lane >> 4) * 8;
            bf16x8 f;
            #pragma unroll
            for (int i = 0; i < 8; i++) f[i] = (short)f2bf_rne(W1[(size_t)(k0 + i) * 128 + jj]);
            af1[jt][kf] = f;
        }
        #pragma unroll
        for (int kf = 0; kf < 4; kf++){
            int k0 = kf * 32 + (lane >> 4) * 8;
            bf16x8 f;
            #pragma unroll
            for (int i = 0; i < 8; i++) f[i] = (short)f2bf_rne(W2[(size_t)(k0 + i) * 128 + jj]);
            af2[jt][kf] = f;
        }
    }
    float b1v[2][4];
    #pragma unroll
    for (int jt = 0; jt < 2; jt++)
        #pragma unroll
        for (int r4 = 0; r4 < 4; r4++)
            b1v[jt][r4] = b1[w4 * 32 + jt * 16 + (lane >> 4) * 4 + r4];

    // ---- fused spmm64: gather y1 rows straight into ybuf (bf16) ----
    for (int rr = w4; rr < 64; rr += 4){
        const int r = blockIdx.x * 64 + rr;
        const int e0 = rowptr[r], e1 = rowptr[r + 1];
        float acc = 0.f;
        int e = e0;
        for (; e + 7 < e1; e += 8){
            int2 a[8];
            #pragma unroll
            for (int q = 0; q < 8; q++) a[q] = cv[e + q];
            #pragma unroll
            for (int q = 0; q < 8; q++)
                acc = fmaf(__int_as_float(a[q].y),
                           __uint_as_float((uint32_t)xb[(size_t)a[q].x * 64 + lane] << 16), acc);
        }
        for (; e < e1; e++){
            int2 a = cv[e];
            acc = fmaf(__int_as_float(a.y),
                       __uint_as_float((uint32_t)xb[(size_t)a.x * 64 + lane] << 16), acc);
        }
        *(ushort*)(ybuf + swz(rr * 128 + lane * 2)) = (ushort)f2bf_rne(acc);
    }
    __syncthreads();

    // pass 1: h1 = y1 @ W1 + b1
    f32x4 acc[2][4];
    #pragma unroll
    for (int jt = 0; jt < 2; jt++)
        #pragma unroll
        for (int ct = 0; ct < 4; ct++)
            #pragma unroll
            for (int r4 = 0; r4 < 4; r4++) acc[jt][ct][r4] = b1v[jt][r4];
    {
        const int lrow = (lane & 15) * 128 + (lane >> 4) * 16;
        __builtin_amdgcn_s_setprio(1);
        #pragma unroll
        for (int kf = 0; kf < 2; kf++){
            #pragma unroll
            for (int ct = 0; ct < 4; ct++){
                int byte = ct * 2048 + kf * 64 + lrow;
                bf16x8 bfr = *(const bf16x8*)(ybuf + swz(byte));
                acc[0][ct] = mfma16(af1[0][kf], bfr, acc[0][ct]);
                acc[1][ct] = mfma16(af1[1][kf], bfr, acc[1][ct]);
            }
        }
        __builtin_amdgcn_s_setprio(0);
    }
    // stage h1 bf16 into hbuf [node][256B] swzE
    #pragma unroll
    for (int jt = 0; jt < 2; jt++){
        #pragma unroll
        for (int ct = 0; ct < 4; ct++){
            int node = ct * 16 + (lane & 15);
            int j2 = (w4 * 32 + jt * 16 + (lane >> 4) * 4) >> 1;
            uint32_t p0 = pkbf(acc[jt][ct][0], acc[jt][ct][1]);
            uint32_t p1 = pkbf(acc[jt][ct][2], acc[jt][ct][3]);
            *(uint2*)(hbuf + swzE(node * 256 + j2 * 4)) = make_uint2(p0, p1);
        }
    }
    __syncthreads();

    // global h1 write (coalesced) + pass 2 MFMA reads (both read hbuf)
    const int snl = tid >> 2, sq = tid & 3;
    {
        uint32_t* dst = h1bf + ((size_t)blockIdx.x * 64 + snl) * 64 + sq * 16;
        #pragma unroll
        for (int q = 0; q < 4; q++)
            *(uint4*)(dst + q * 4) = *(uint4*)(hbuf + swzE(snl * 256 + sq * 64 + q * 16));
    }
    f32x4 acc2[2][4];
    #pragma unroll
    for (int jt = 0; jt < 2; jt++)
        #pragma unroll
        for (int ct = 0; ct < 4; ct++)
            #pragma unroll
            for (int r4 = 0; r4 < 4; r4++) acc2[jt][ct][r4] = 0.f;
    {
        const int lrow = (lane & 15) * 256 + (lane >> 4) * 16;
        __builtin_amdgcn_s_setprio(1);
        #pragma unroll
        for (int kf = 0; kf < 4; kf++){
            #pragma unroll
            for (int ct = 0; ct < 4; ct++){
                int byte = ct * 4096 + kf * 64 + lrow;
                bf16x8 bfr = *(const bf16x8*)(hbuf + swzE(byte));
                acc2[0][ct] = mfma16(af2[0][kf], bfr, acc2[0][ct]);
                acc2[1][ct] = mfma16(af2[1][kf], bfr, acc2[1][ct]);
            }
        }
        __builtin_amdgcn_s_setprio(0);
    }
    __syncthreads();   // all hbuf reads done before z-stage overwrites

    #pragma unroll
    for (int jt = 0; jt < 2; jt++){
        #pragma unroll
        for (int ct = 0; ct < 4; ct++){
            int node = ct * 16 + (lane & 15);
            int j2 = (w4 * 32 + jt * 16 + (lane >> 4) * 4) >> 1;
            uint32_t p0 = pkbf(acc2[jt][ct][0], acc2[jt][ct][1]);
            uint32_t p1 = pkbf(acc2[jt][ct][2], acc2[jt][ct][3]);
            *(uint2*)(hbuf + swzE(node * 256 + j2 * 4)) = make_uint2(p0, p1);
        }
    }
    __syncthreads();
    {
        uint32_t* dst = zbf + ((size_t)blockIdx.x * 64 + snl) * 64 + sq * 16;
        #pragma unroll
        for (int q = 0; q < 4; q++)
            *(uint4*)(dst + q * 4) = *(uint4*)(hbuf + swzE(snl * 256 + sq * 64 + q * 16));
    }
}

// ---------------- merged scoring: one block per b handles user/pos/4 negs ----------------
__global__ __launch_bounds__(128)
void score_kernel(const uint32_t* __restrict__ h1bf, const float* __restrict__ h2c,
                  const float* __restrict__ lin_w, const float* __restrict__ lin_b,
                  const int* __restrict__ user, const int* __restrict__ pos_item,
                  const int* __restrict__ neg_item, float* __restrict__ bloss)
{
    const int b = blockIdx.x, j = threadIdx.x;
    const int un = NBO + user[b];
    const int pn = NBO + NBU + pos_item[b];
    const int n0 = NBO + NBU + neg_item[b];
    const int n1 = NBO + NBU + neg_item[BSZ + b];
    const int n2 = NBO + NBU + neg_item[2 * BSZ + b];
    const int n3 = NBO + NBU + neg_item[3 * BSZ + b];
    const float* lw = lin_w + j * 256;
    const uint32_t* h1u = h1bf + (size_t)un * 64;  const float* h2u = h2c + (size_t)b * 128;
    const uint32_t* h1p = h1bf + (size_t)pn * 64;  const float* h2p = h2c + (size_t)(BSZ + b) * 128;
    const uint32_t* h1a = h1bf + (size_t)n0 * 64;  const float* h2a = h2c + (size_t)(2 * BSZ + b) * 128;
    const uint32_t* h1b = h1bf + (size_t)n1 * 64;  const float* h2b = h2c + (size_t)(3 * BSZ + b) * 128;
    const uint32_t* h1c = h1bf + (size_t)n2 * 64;  const float* h2cc = h2c + (size_t)(4 * BSZ + b) * 128;
    const uint32_t* h1d = h1bf + (size_t)n3 * 64;  const float* h2d = h2c + (size_t)(5 * BSZ + b) * 128;
    float lb = lin_b[j];
    float ua = lb, pa = lb, a0 = lb, a1 = lb, a2 = lb, a3 = lb;
    #pragma unroll 4
    for (int m2 = 0; m2 < 64; m2++){
        float w1l = lw[2 * m2], w1h = lw[2 * m2 + 1];
        uint32_t wu = h1u[m2], wp = h1p[m2], wa = h1a[m2], wb = h1b[m2], wc = h1c[m2], wd = h1d[m2];
        ua = fmaf(bfu_lo(wu), w1l, ua); ua = fmaf(bfu_hi(wu), w1h, ua);
        pa = fmaf(bfu_lo(wp), w1l, pa); pa = fmaf(bfu_hi(wp), w1h, pa);
        a0 = fmaf(bfu_lo(wa), w1l, a0); a0 = fmaf(bfu_hi(wa), w1h, a0);
        a1 = fmaf(bfu_lo(wb), w1l, a1); a1 = fmaf(bfu_hi(wb), w1h, a1);
        a2 = fmaf(bfu_lo(wc), w1l, a2); a2 = fmaf(bfu_hi(wc), w1h, a2);
        a3 = fmaf(bfu_lo(wd), w1l, a3); a3 = fmaf(bfu_hi(wd), w1h, a3);
    }
    #pragma unroll 4
    for (int m = 0; m < 128; m++){
        float w2 = lw[128 + m];
        ua = fmaf(h2u[m], w2, ua);
        pa = fmaf(h2p[m], w2, pa);
        a0 = fmaf(h2a[m], w2, a0);
        a1 = fmaf(h2b[m], w2, a1);
        a2 = fmaf(h2cc[m], w2, a2);
        a3 = fmaf(h2d[m], w2, a3);
    }
    float dp = ua * pa;
    float dn = ua * (a0 + a1 + a2 + a3);
    #pragma unroll
    for (int off = 32; off > 0; off >>= 1){
        dp += __shfl_down(dp, off, 64);
        dn += __shfl_down(dn, off, 64);
    }
    __shared__ float red[4];
    if ((j & 63) == 0){ red[(j >> 6) * 2] = dp; red[(j >> 6) * 2 + 1] = dn; }
    __syncthreads();
    if (j == 0){
        float P = red[0] + red[2];
        float N = red[1] + red[3];
        float v = 0.25f * N - P + 1.0f;
        bloss[b] = fminf(fmaxf(v, 1e-6f), 1e4f);
    }
}

__global__ __launch_bounds__(1024)
void loss_kernel(const float* __restrict__ bloss, float* __restrict__ out)
{
    const int t = threadIdx.x;
    float v = bloss[t];
    #pragma unroll
    for (int off = 32; off > 0; off >>= 1) v += __shfl_down(v, off, 64);
    __shared__ float red[16];
    if ((t & 63) == 0) red[t >> 6] = v;
    __syncthreads();
    if (t == 0){
        float s = 0.f;
        #pragma unroll
        for (int i = 0; i < 16; i++) s += red[i];
        out[0] = s;
    }
}

extern "C" void kernel_launch(void* const* d_in, const int* in_sizes, int n_in,
                              void* d_out, int out_size, void* d_ws, size_t ws_size,
                              hipStream_t stream)
{
    const float* word_emb  = (const float*)d_in[0];
    const float* other_pos = (const float*)d_in[1];
    const float* user_pos  = (const float*)d_in[2];
    const float* item_pos  = (const float*)d_in[3];
    const float* w_ih0 = (const float*)d_in[4];
    const float* w_hh0 = (const float*)d_in[5];
    const float* b_ih0 = (const float*)d_in[6];
    const float* b_hh0 = (const float*)d_in[7];
    const float* w_ih1 = (const float*)d_in[8];
    const float* w_hh1 = (const float*)d_in[9];
    const float* b_ih1 = (const float*)d_in[10];
    const float* b_hh1 = (const float*)d_in[11];
    const float* conv1_w = (const float*)d_in[12];
    const float* conv1_b = (const float*)d_in[13];
    const float* conv2_w = (const float*)d_in[14];
    const float* conv2_b = (const float*)d_in[15];
    const float* lin_w   = (const float*)d_in[16];
    const float* lin_b   = (const float*)d_in[17];
    const int* adj_row = (const int*)d_in[18];
    const int* adj_col = (const int*)d_in[19];
    const float* adj_vals = (const float*)d_in[20];
    const int* lookup   = (const int*)d_in[21];
    const int* user     = (const int*)d_in[22];
    const int* pos_item = (const int*)d_in[23];
    const int* neg_item = (const int*)d_in[24];

    float* ws = (float*)d_ws;

    uint32_t* h1bf = (uint32_t*)ws;                        // [N*64]  4,608,000 w
    uint32_t* zbf  = h1bf + 4608000;                       // [N*64]  4,608,000 w
    float*    h2c  = (float*)(zbf + 4608000);              // [NSLOT*128] 786,432 w
    uint32_t* abf  = (uint32_t*)(h2c + 786432);            // [N*32]  2,304,000 w
    uint32_t* ebf  = abf + 2304000;                        // [(V+1)*32] 1,600,032 w
    float*    bloss = (float*)(ebf + 1600032);             // [1024]
    int* rowptr = (int*)(bloss + 1088);                    // [NNODES+1]
    int* cursor = rowptr + 72004;
    int* deg    = cursor + 72004;
    int* bsum   = deg + 72004;                             // [NSB]
    int2* cv    = (int2*)(bsum + 128);                     // [NEDGE]

    (void)hipMemsetAsync(deg, 0, NNODES * sizeof(int), stream);

    prep_kernel<<<EB_BLKS + DEG_BLKS, 256, 0, stream>>>(word_emb, ebf, adj_row, deg);

    scan1_kernel<<<NSB, 1024, 0, stream>>>(deg, rowptr, bsum);
    scan3_kernel<<<NSB, 1024, 0, stream>>>(deg, rowptr, bsum, cursor);
    scat_kernel<<<(NEDGE + 255) / 256, 256, 0, stream>>>(adj_row, adj_col, adj_vals, cursor, cv);

    gru_kernel<<<NNODES / 64, 512, 0, stream>>>(
        ebf, lookup, w_ih0, w_hh0, b_ih0, b_hh0,
        w_ih1, w_hh1, b_ih1, b_hh1,
        other_pos, user_pos, item_pos, abf);

    gemm12_mfma<<<NNODES / 64, 256, 0, stream>>>(rowptr, cv, (const ushort*)abf,
                                                 conv1_w, conv1_b, conv2_w, h1bf, zbf);

    spmm128_slots<<<NSLOT / 4, 256, 0, stream>>>(rowptr, cv, zbf, conv2_b,
                                                 user, pos_item, neg_item, h2c);

    score_kernel<<<BSZ, 128, 0, stream>>>(h1bf, h2c, lin_w, lin_b, user, pos_item, neg_item, bloss);

    loss_kernel<<<1, 1024, 0, stream>>>(bloss, (float*)d_out);
}

// Round 14
// 526.844 us; speedup vs baseline: 1.1192x; 1.1192x over previous
//
#include <hip/hip_runtime.h>
#include <hip/hip_bf16.h>
#include <stdint.h>

#define NNODES 72000
#define NBO 2000
#define NBU 20000
#define NBI 50000
#define NEDGE 1152000
#define VOCAB 50000
#define TSEQ 20
#define BSZ 1024
#define KNEG 4
#define NSB 71     // scan blocks: 71*1024 >= 72000
#define NSLOT (2 * BSZ + KNEG * BSZ)   // 6144 scored slots: user | pos | neg
#define EB_ELEM ((VOCAB + 1) * 32)     // 1,600,032 packed words
#define EB_BLKS ((EB_ELEM + 255) / 256)
#define DEG_BLKS ((NEDGE + 255) / 256)

typedef __attribute__((ext_vector_type(8))) short bf16x8;
typedef __attribute__((ext_vector_type(4))) float f32x4;

__device__ __forceinline__ float rcp_fast(float x){ return __builtin_amdgcn_rcpf(x); }
__device__ __forceinline__ float sigmoidf_(float x){ return rcp_fast(1.f + __expf(-x)); }
__device__ __forceinline__ float tanhf_(float x){
    float xx = fminf(fmaxf(x, -15.f), 15.f);
    float e = __expf(-2.f * xx);
    return (1.f - e) * rcp_fast(1.f + e);
}
__device__ __forceinline__ uint32_t f2bf_rne(float f){
    uint32_t u = __float_as_uint(f);
    return (u + 0x7fffu + ((u >> 16) & 1u)) >> 16;
}
// HW packed convert: 2 fp32 -> 2 bf16 (v_cvt_pk_bf16_f32); memcpy = reg move
__device__ __forceinline__ uint32_t pkbf(float lo, float hi){
    __hip_bfloat162 h = __float22bfloat162_rn(make_float2(lo, hi));
    uint32_t r;
    __builtin_memcpy(&r, &h, 4);
    return r;
}
__device__ __forceinline__ float bfu_lo(uint32_t p){ return __uint_as_float(p << 16); }
__device__ __forceinline__ float bfu_hi(uint32_t p){ return __uint_as_float(p & 0xffff0000u); }

__device__ __forceinline__ f32x4 mfma16(bf16x8 a, bf16x8 b, f32x4 c){
    return __builtin_amdgcn_mfma_f32_16x16x32_bf16(a, b, c, 0, 0, 0);
}

// XOR swizzle for 128B-row LDS tiles (16B slots spread per 8-row stripe)
__device__ __forceinline__ int swz(int b){ return b ^ (((b >> 7) & 7) << 4); }
// XOR swizzle for 256B-row tiles
__device__ __forceinline__ int swzE(int b){ return b ^ (((b >> 8) & 7) << 4); }

// ---------------- MFMA GRU (r8/r9 proven: 512 thr, 2 barriers/t, no spill) ----------------

__device__ __forceinline__ void gru_layer_step(
    const char* __restrict__ xsrc, const char* __restrict__ hsrc,
    const bf16x8 (&wih)[3][2], const bf16x8 (&whh)[3][2],
    const f32x4& rb, const f32x4& zb, const f32x4& ib, const f32x4& hb,
    f32x4 (&hreg)[2], int lane, int ctb)
{
    f32x4 ar[2], az[2], ain[2], ahn[2];
    #pragma unroll
    for (int c = 0; c < 2; c++){ ar[c] = rb; az[c] = zb; ain[c] = ib; ahn[c] = hb; }
    const int lrow = (lane & 15) * 128 + (lane >> 4) * 16;
    __builtin_amdgcn_s_setprio(1);
    #pragma unroll
    for (int kf = 0; kf < 2; kf++){
        #pragma unroll
        for (int c = 0; c < 2; c++){
            int byte = (ctb + c) * 2048 + kf * 64 + lrow;
            bf16x8 bx = *(const bf16x8*)(xsrc + swz(byte));
            bf16x8 bh = *(const bf16x8*)(hsrc + swz(byte));
            ar[c]  = mfma16(wih[0][kf], bx, ar[c]);
            ar[c]  = mfma16(whh[0][kf], bh, ar[c]);
            az[c]  = mfma16(wih[1][kf], bx, az[c]);
            az[c]  = mfma16(whh[1][kf], bh, az[c]);
            ain[c] = mfma16(wih[2][kf], bx, ain[c]);
            ahn[c] = mfma16(whh[2][kf], bh, ahn[c]);
        }
    }
    __builtin_amdgcn_s_setprio(0);
    #pragma unroll
    for (int c = 0; c < 2; c++){
        #pragma unroll
        for (int r4 = 0; r4 < 4; r4++){
            float rg = sigmoidf_(ar[c][r4]);
            float zg = sigmoidf_(az[c][r4]);
            float ng = tanhf_(fmaf(rg, ahn[c][r4], ain[c][r4]));
            hreg[c][r4] = fmaf(zg, hreg[c][r4] - ng, ng);
        }
    }
}

__device__ __forceinline__ void write_h(char* __restrict__ dst,
                                        const f32x4 (&hreg)[2], int w4, int lane, int ctb)
{
    #pragma unroll
    for (int c = 0; c < 2; c++){
        uint32_t p0 = pkbf(hreg[c][0], hreg[c][1]);
        uint32_t p1 = pkbf(hreg[c][2], hreg[c][3]);
        int byte = ((ctb + c) * 16 + (lane & 15)) * 128 + w4 * 32 + (lane >> 4) * 8;
        *(uint2*)(dst + swz(byte)) = make_uint2(p0, p1);
    }
}

__global__ __launch_bounds__(512, 2)
void gru_kernel(const uint32_t* __restrict__ ebf,
                const int* __restrict__ lookup,
                const float* __restrict__ w_ih0, const float* __restrict__ w_hh0,
                const float* __restrict__ b_ih0, const float* __restrict__ b_hh0,
                const float* __restrict__ w_ih1, const float* __restrict__ w_hh1,
                const float* __restrict__ b_ih1, const float* __restrict__ b_hh1,
                const float* __restrict__ other_pos, const float* __restrict__ user_pos,
                const float* __restrict__ item_pos,
                uint32_t* __restrict__ abf)
{
    __shared__ __align__(16) char xbuf[2][8192];
    __shared__ __align__(16) char h0buf[2][8192];
    __shared__ __align__(16) char h1buf[2][8192];

    const int tid  = threadIdx.x;
    const int lane = tid & 63;
    const int wave = tid >> 6;
    const int w4   = wave & 3;
    const int ctb  = (wave >> 2) * 2;

    const float* mats[4] = { w_ih0, w_hh0, w_ih1, w_hh1 };
    bf16x8 wf[4][3][2];
    #pragma unroll
    for (int m = 0; m < 4; m++){
        #pragma unroll
        for (int g = 0; g < 3; g++){
            #pragma unroll
            for (int kf = 0; kf < 2; kf++){
                int row = (g * 4 + w4) * 16 + (lane & 15);
                int k0  = kf * 32 + (lane >> 4) * 8;
                const float* p = mats[m] + row * 64 + k0;
                float4 a = *(const float4*)p;
                float4 b = *(const float4*)(p + 4);
                bf16x8 f;
                f[0] = (short)f2bf_rne(a.x); f[1] = (short)f2bf_rne(a.y);
                f[2] = (short)f2bf_rne(a.z); f[3] = (short)f2bf_rne(a.w);
                f[4] = (short)f2bf_rne(b.x); f[5] = (short)f2bf_rne(b.y);
                f[6] = (short)f2bf_rne(b.z); f[7] = (short)f2bf_rne(b.w);
                wf[m][g][kf] = f;
            }
        }
    }

    const int bofs = w4 * 16 + (lane >> 4) * 4;
    f32x4 rb0, zb0, ib0, hb0, rb1, zb1, ib1, hb1;
    #pragma unroll
    for (int r4 = 0; r4 < 4; r4++){
        rb0[r4] = b_ih0[bofs + r4]       + b_hh0[bofs + r4];
        zb0[r4] = b_ih0[64 + bofs + r4]  + b_hh0[64 + bofs + r4];
        ib0[r4] = b_ih0[128 + bofs + r4];
        hb0[r4] = b_hh0[128 + bofs + r4];
        rb1[r4] = b_ih1[bofs + r4]       + b_hh1[bofs + r4];
        zb1[r4] = b_ih1[64 + bofs + r4]  + b_hh1[64 + bofs + r4];
        ib1[r4] = b_ih1[128 + bofs + r4];
        hb1[r4] = b_hh1[128 + bofs + r4];
    }

    {
        uint4 z4 = make_uint4(0, 0, 0, 0);
        ((uint4*)h0buf[0])[tid] = z4;
        ((uint4*)h1buf[0])[tid] = z4;
    }
    const int pnl = tid >> 3, pdg = tid & 7;
    const long nodeP = (long)blockIdx.x * 64 + pnl;
    const int sbyte = pnl * 128 + pdg * 16;
    {
        int idx = lookup[nodeP * TSEQ + 0];
        uint4 a = ((const uint4*)(ebf + (size_t)idx * 32))[pdg];
        *(uint4*)(xbuf[0] + swz(sbyte)) = a;
    }
    __syncthreads();

    f32x4 h0reg[2], h1reg[2];
    #pragma unroll
    for (int c = 0; c < 2; c++){
        #pragma unroll
        for (int r4 = 0; r4 < 4; r4++){ h0reg[c][r4] = 0.f; h1reg[c][r4] = 0.f; }
    }

    for (int t = 0; t < TSEQ; t++){
        const int p = t & 1, q = p ^ 1;
        const bool pf = (t + 1 < TSEQ);
        uint4 xa;
        if (pf){
            int idx = lookup[nodeP * TSEQ + t + 1];
            xa = ((const uint4*)(ebf + (size_t)idx * 32))[pdg];
        }
        gru_layer_step(xbuf[p], h0buf[p], wf[0], wf[1], rb0, zb0, ib0, hb0, h0reg, lane, ctb);
        write_h(h0buf[q], h0reg, w4, lane, ctb);
        __syncthreads();
        gru_layer_step(h0buf[q], h1buf[p], wf[2], wf[3], rb1, zb1, ib1, hb1, h1reg, lane, ctb);
        write_h(h1buf[q], h1reg, w4, lane, ctb);
        if (pf) *(uint4*)(xbuf[q] + swz(sbyte)) = xa;
        __syncthreads();
    }

    float* xstage = (float*)xbuf;
    #pragma unroll
    for (int c = 0; c < 2; c++){
        int nl = (ctb + c) * 16 + (lane & 15);
        int byte = nl * 256 + w4 * 64 + (lane >> 4) * 16;
        *(float4*)((char*)xstage + swzE(byte)) =
            make_float4(h1reg[c][0], h1reg[c][1], h1reg[c][2], h1reg[c][3]);
    }
    __syncthreads();
    {
        long node = nodeP;
        const float* pp; long off;
        if (node < NBO)            { pp = other_pos; off = node; }
        else if (node < NBO + NBU) { pp = user_pos;  off = node - NBO; }
        else                       { pp = item_pos;  off = node - NBO - NBU; }
        const float* pr = pp + off * 64 + pdg * 8;
        float4 pa = *(const float4*)pr;
        float4 pb = *(const float4*)(pr + 4);
        int byte = pnl * 256 + pdg * 32;
        float4 ha = *(float4*)((char*)xstage + swzE(byte));
        float4 hb2 = *(float4*)((char*)xstage + swzE(byte + 16));
        uint4 ov;
        ov.x = pkbf(pa.x + ha.x, pa.y + ha.y);
        ov.y = pkbf(pa.z + ha.z, pa.w + ha.w);
        ov.z = pkbf(pb.x + hb2.x, pb.y + hb2.y);
        ov.w = pkbf(pb.z + hb2.z, pb.w + hb2.w);
        ((uint4*)abf)[node * 8 + pdg] = ov;
    }
}

// ---------------- prep: emb2bf (blocks [0,EB_BLKS)) + deg atomics (rest) ----------------
__global__ __launch_bounds__(256)
void prep_kernel(const float* __restrict__ we, uint32_t* __restrict__ ebf,
                 const int* __restrict__ row, int* __restrict__ deg)
{
    if (blockIdx.x < EB_BLKS){
        size_t i = (size_t)blockIdx.x * 256 + threadIdx.x;
        if (i < (size_t)EB_ELEM){
            float2 v = ((const float2*)we)[i];
            ebf[i] = pkbf(v.x, v.y);
        }
    } else {
        int e = (blockIdx.x - EB_BLKS) * 256 + threadIdx.x;
        if (e < NEDGE) atomicAdd(&deg[row[e]], 1);
    }
}

// ---------------- CSR build ----------------
__global__ __launch_bounds__(1024)
void scan1_kernel(const int* __restrict__ deg, int* __restrict__ rowptr, int* __restrict__ bsum)
{
    __shared__ int wsum[16];
    const int tid = threadIdx.x, lane = tid & 63, w = tid >> 6;
    const int i = blockIdx.x * 1024 + tid;
    int v = (i < NNODES) ? deg[i] : 0;
    int s = v;
    #pragma unroll
    for (int o = 1; o < 64; o <<= 1){
        int t = __shfl_up(s, o, 64);
        if (lane >= o) s += t;
    }
    if (lane == 63) wsum[w] = s;
    __syncthreads();
    if (w == 0){
        int t = (lane < 16) ? wsum[lane] : 0;
        #pragma unroll
        for (int o = 1; o < 16; o <<= 1){
            int u = __shfl_up(t, o, 64);
            if (lane >= o) t += u;
        }
        if (lane < 16) wsum[lane] = t;
    }
    __syncthreads();
    int incl = s + ((w > 0) ? wsum[w - 1] : 0);
    if (i < NNODES) rowptr[i + 1] = incl;
    if (tid == 0) bsum[blockIdx.x] = wsum[15];
}

// scan3 with inline block-offset reduce (replaces scan2)
__global__ __launch_bounds__(1024)
void scan3_kernel(const int* __restrict__ deg, int* __restrict__ rowptr,
                  const int* __restrict__ bsum, int* __restrict__ cursor)
{
    __shared__ int boff_sh;
    const int tid = threadIdx.x;
    if (tid < 64){
        int v = 0;
        for (int k = tid; k < blockIdx.x; k += 64) v += bsum[k];
        #pragma unroll
        for (int o = 32; o > 0; o >>= 1) v += __shfl_down(v, o, 64);
        if (tid == 0) boff_sh = v;
    }
    __syncthreads();
    const int i = blockIdx.x * 1024 + tid;
    if (i < NNODES){
        int r = rowptr[i + 1] + boff_sh;
        rowptr[i + 1] = r;
        cursor[i] = r - deg[i];
    }
    if (i == 0) rowptr[0] = 0;
}

__global__ __launch_bounds__(256)
void scat_kernel(const int* __restrict__ row, const int* __restrict__ col,
                 const float* __restrict__ vals, int* __restrict__ cursor,
                 int2* __restrict__ cv)
{
    int e = blockIdx.x * 256 + threadIdx.x;
    if (e < NEDGE){
        int p = atomicAdd(&cursor[row[e]], 1);
        cv[p] = make_int2(col[e], __float_as_int(vals[e]));
    }
}

// ---------------- CSR spmm64: one wave per row, high TLP, writes bf16 y1 ----------------
__global__ __launch_bounds__(256)
void spmm64_csr(const int* __restrict__ rowptr, const int2* __restrict__ cv,
                const ushort* __restrict__ xb, ushort* __restrict__ y1bf)
{
    const int r = blockIdx.x * 4 + (threadIdx.x >> 6);
    const int lane = threadIdx.x & 63;
    const int e0 = rowptr[r], e1 = rowptr[r + 1];
    float acc = 0.f;
    int e = e0;
    for (; e + 7 < e1; e += 8){
        int2 a[8];
        #pragma unroll
        for (int q = 0; q < 8; q++) a[q] = cv[e + q];
        float x[8];
        #pragma unroll
        for (int q = 0; q < 8; q++)
            x[q] = __uint_as_float((uint32_t)xb[(size_t)a[q].x * 64 + lane] << 16);
        #pragma unroll
        for (int q = 0; q < 8; q++) acc = fmaf(__int_as_float(a[q].y), x[q], acc);
    }
    for (; e + 3 < e1; e += 4){
        int2 a0 = cv[e], a1 = cv[e + 1], a2 = cv[e + 2], a3 = cv[e + 3];
        float x0 = __uint_as_float((uint32_t)xb[(size_t)a0.x * 64 + lane] << 16);
        float x1 = __uint_as_float((uint32_t)xb[(size_t)a1.x * 64 + lane] << 16);
        float x2 = __uint_as_float((uint32_t)xb[(size_t)a2.x * 64 + lane] << 16);
        float x3 = __uint_as_float((uint32_t)xb[(size_t)a3.x * 64 + lane] << 16);
        acc = fmaf(__int_as_float(a0.y), x0, acc);
        acc = fmaf(__int_as_float(a1.y), x1, acc);
        acc = fmaf(__int_as_float(a2.y), x2, acc);
        acc = fmaf(__int_as_float(a3.y), x3, acc);
    }
    for (; e < e1; e++){
        int2 a = cv[e];
        acc = fmaf(__int_as_float(a.y),
                   __uint_as_float((uint32_t)xb[(size_t)a.x * 64 + lane] << 16), acc);
    }
    y1bf[(size_t)r * 64 + lane] = (ushort)f2bf_rne(acc);
}

// h2c[slot] = bias + sum_e A[node(slot),c] * z2[c]  -- only 6144 scored slots
__global__ __launch_bounds__(256)
void spmm128_slots(const int* __restrict__ rowptr, const int2* __restrict__ cv,
                   const uint32_t* __restrict__ zb, const float* __restrict__ b2,
                   const int* __restrict__ user, const int* __restrict__ pos_item,
                   const int* __restrict__ neg_item, float* __restrict__ h2c)
{
    const int slot = blockIdx.x * 4 + (threadIdx.x >> 6);
    const int lane = threadIdx.x & 63;
    int r;
    if (slot < BSZ)            r = NBO + user[slot];
    else if (slot < 2 * BSZ)   r = NBO + NBU + pos_item[slot - BSZ];
    else                       r = NBO + NBU + neg_item[slot - 2 * BSZ];
    const int e0 = rowptr[r], e1 = rowptr[r + 1];
    float2 acc = make_float2(b2[2 * lane], b2[2 * lane + 1]);
    int e = e0;
    for (; e + 1 < e1; e += 2){
        int2 a0 = cv[e], a1 = cv[e + 1];
        uint32_t z0 = zb[(size_t)a0.x * 64 + lane];
        uint32_t z1 = zb[(size_t)a1.x * 64 + lane];
        float v0 = __int_as_float(a0.y), v1 = __int_as_float(a1.y);
        acc.x = fmaf(v0, bfu_lo(z0), acc.x);
        acc.y = fmaf(v0, bfu_hi(z0), acc.y);
        acc.x = fmaf(v1, bfu_lo(z1), acc.x);
        acc.y = fmaf(v1, bfu_hi(z1), acc.y);
    }
    if (e < e1){
        int2 a = cv[e];
        uint32_t z0 = zb[(size_t)a.x * 64 + lane];
        float v = __int_as_float(a.y);
        acc.x = fmaf(v, bfu_lo(z0), acc.x);
        acc.y = fmaf(v, bfu_hi(z0), acc.y);
    }
    *(float2*)(h2c + (size_t)slot * 128 + 2 * lane) = acc;
}

// ---- fused dense: h1 = y1@W1+b1 (write bf16), z2 = h1@W2 (write bf16) ----
// 64 nodes/block, 4 waves; y1 read as packed bf16 (direct LDS stage).
__global__ __launch_bounds__(256, 2)
void gemm12_mfma(const uint32_t* __restrict__ y1bf,
                 const float* __restrict__ W1, const float* __restrict__ b1,
                 const float* __restrict__ W2,
                 uint32_t* __restrict__ h1bf, uint32_t* __restrict__ zbf)
{
    __shared__ __align__(16) char ybuf[8192];    // [64 nodes][128B bf16], swz
    __shared__ __align__(16) char hbuf[16384];   // [64 nodes][256B bf16], swzE
    const int tid = threadIdx.x, lane = tid & 63, w4 = tid >> 6;

    bf16x8 af1[2][2], af2[2][4];
    #pragma unroll
    for (int jt = 0; jt < 2; jt++){
        int jj = w4 * 32 + jt * 16 + (lane & 15);
        #pragma unroll
        for (int kf = 0; kf < 2; kf++){
            int k0 = kf * 32 + (lane >> 4) * 8;
            bf16x8 f;
            #pragma unroll
            for (int i = 0; i < 8; i++) f[i] = (short)f2bf_rne(W1[(size_t)(k0 + i) * 128 + jj]);
            af1[jt][kf] = f;
        }
        #pragma unroll
        for (int kf = 0; kf < 4; kf++){
            int k0 = kf * 32 + (lane >> 4) * 8;
            bf16x8 f;
            #pragma unroll
            for (int i = 0; i < 8; i++) f[i] = (short)f2bf_rne(W2[(size_t)(k0 + i) * 128 + jj]);
            af2[jt][kf] = f;
        }
    }
    float b1v[2][4];
    #pragma unroll
    for (int jt = 0; jt < 2; jt++)
        #pragma unroll
        for (int r4 = 0; r4 < 4; r4++)
            b1v[jt][r4] = b1[w4 * 32 + jt * 16 + (lane >> 4) * 4 + r4];

    // stage y1 tile (already bf16): 4 threads/node, 32B each
    const int snl = tid >> 2, sq = tid & 3;
    {
        const uint32_t* yr = y1bf + ((size_t)blockIdx.x * 64 + snl) * 32 + sq * 8;
        uint4 p0 = *(const uint4*)yr;
        uint4 p1 = *(const uint4*)(yr + 4);
        int base = snl * 128 + sq * 32;
        *(uint4*)(ybuf + swz(base))      = p0;
        *(uint4*)(ybuf + swz(base + 16)) = p1;
    }
    __syncthreads();

    // pass 1: h1 = y1 @ W1 + b1
    f32x4 acc[2][4];
    #pragma unroll
    for (int jt = 0; jt < 2; jt++)
        #pragma unroll
        for (int ct = 0; ct < 4; ct++)
            #pragma unroll
            for (int r4 = 0; r4 < 4; r4++) acc[jt][ct][r4] = b1v[jt][r4];
    {
        const int lrow = (lane & 15) * 128 + (lane >> 4) * 16;
        __builtin_amdgcn_s_setprio(1);
        #pragma unroll
        for (int kf = 0; kf < 2; kf++){
            #pragma unroll
            for (int ct = 0; ct < 4; ct++){
                int byte = ct * 2048 + kf * 64 + lrow;
                bf16x8 bfr = *(const bf16x8*)(ybuf + swz(byte));
                acc[0][ct] = mfma16(af1[0][kf], bfr, acc[0][ct]);
                acc[1][ct] = mfma16(af1[1][kf], bfr, acc[1][ct]);
            }
        }
        __builtin_amdgcn_s_setprio(0);
    }
    // stage h1 bf16 into hbuf [node][256B] swzE
    #pragma unroll
    for (int jt = 0; jt < 2; jt++){
        #pragma unroll
        for (int ct = 0; ct < 4; ct++){
            int node = ct * 16 + (lane & 15);
            int j2 = (w4 * 32 + jt * 16 + (lane >> 4) * 4) >> 1;
            uint32_t p0 = pkbf(acc[jt][ct][0], acc[jt][ct][1]);
            uint32_t p1 = pkbf(acc[jt][ct][2], acc[jt][ct][3]);
            *(uint2*)(hbuf + swzE(node * 256 + j2 * 4)) = make_uint2(p0, p1);
        }
    }
    __syncthreads();

    // global h1 write (coalesced) + pass 2 MFMA reads (both read hbuf)
    {
        uint32_t* dst = h1bf + ((size_t)blockIdx.x * 64 + snl) * 64 + sq * 16;
        #pragma unroll
        for (int q = 0; q < 4; q++)
            *(uint4*)(dst + q * 4) = *(uint4*)(hbuf + swzE(snl * 256 + sq * 64 + q * 16));
    }
    f32x4 acc2[2][4];
    #pragma unroll
    for (int jt = 0; jt < 2; jt++)
        #pragma unroll
        for (int ct = 0; ct < 4; ct++)
            #pragma unroll
            for (int r4 = 0; r4 < 4; r4++) acc2[jt][ct][r4] = 0.f;
    {
        const int lrow = (lane & 15) * 256 + (lane >> 4) * 16;
        __builtin_amdgcn_s_setprio(1);
        #pragma unroll
        for (int kf = 0; kf < 4; kf++){
            #pragma unroll
            for (int ct = 0; ct < 4; ct++){
                int byte = ct * 4096 + kf * 64 + lrow;
                bf16x8 bfr = *(const bf16x8*)(hbuf + swzE(byte));
                acc2[0][ct] = mfma16(af2[0][kf], bfr, acc2[0][ct]);
                acc2[1][ct] = mfma16(af2[1][kf], bfr, acc2[1][ct]);
            }
        }
        __builtin_amdgcn_s_setprio(0);
    }
    __syncthreads();   // all hbuf reads done before z-stage overwrites

    #pragma unroll
    for (int jt = 0; jt < 2; jt++){
        #pragma unroll
        for (int ct = 0; ct < 4; ct++){
            int node = ct * 16 + (lane & 15);
            int j2 = (w4 * 32 + jt * 16 + (lane >> 4) * 4) >> 1;
            uint32_t p0 = pkbf(acc2[jt][ct][0], acc2[jt][ct][1]);
            uint32_t p1 = pkbf(acc2[jt][ct][2], acc2[jt][ct][3]);
            *(uint2*)(hbuf + swzE(node * 256 + j2 * 4)) = make_uint2(p0, p1);
        }
    }
    __syncthreads();
    {
        uint32_t* dst = zbf + ((size_t)blockIdx.x * 64 + snl) * 64 + sq * 16;
        #pragma unroll
        for (int q = 0; q < 4; q++)
            *(uint4*)(dst + q * 4) = *(uint4*)(hbuf + swzE(snl * 256 + sq * 64 + q * 16));
    }
}

// ---------------- merged scoring: one block per b handles user/pos/4 negs ----------------
__global__ __launch_bounds__(128)
void score_kernel(const uint32_t* __restrict__ h1bf, const float* __restrict__ h2c,
                  const float* __restrict__ lin_w, const float* __restrict__ lin_b,
                  const int* __restrict__ user, const int* __restrict__ pos_item,
                  const int* __restrict__ neg_item, float* __restrict__ bloss)
{
    const int b = blockIdx.x, j = threadIdx.x;
    const int un = NBO + user[b];
    const int pn = NBO + NBU + pos_item[b];
    const int n0 = NBO + NBU + neg_item[b];
    const int n1 = NBO + NBU + neg_item[BSZ + b];
    const int n2 = NBO + NBU + neg_item[2 * BSZ + b];
    const int n3 = NBO + NBU + neg_item[3 * BSZ + b];
    const float* lw = lin_w + j * 256;
    const uint32_t* h1u = h1bf + (size_t)un * 64;  const float* h2u = h2c + (size_t)b * 128;
    const uint32_t* h1p = h1bf + (size_t)pn * 64;  const float* h2p = h2c + (size_t)(BSZ + b) * 128;
    const uint32_t* h1a = h1bf + (size_t)n0 * 64;  const float* h2a = h2c + (size_t)(2 * BSZ + b) * 128;
    const uint32_t* h1b = h1bf + (size_t)n1 * 64;  const float* h2b = h2c + (size_t)(3 * BSZ + b) * 128;
    const uint32_t* h1c = h1bf + (size_t)n2 * 64;  const float* h2cc = h2c + (size_t)(4 * BSZ + b) * 128;
    const uint32_t* h1d = h1bf + (size_t)n3 * 64;  const float* h2d = h2c + (size_t)(5 * BSZ + b) * 128;
    float lb = lin_b[j];
    float ua = lb, pa = lb, a0 = lb, a1 = lb, a2 = lb, a3 = lb;
    #pragma unroll 4
    for (int m2 = 0; m2 < 64; m2++){
        float w1l = lw[2 * m2], w1h = lw[2 * m2 + 1];
        uint32_t wu = h1u[m2], wp = h1p[m2], wa = h1a[m2], wb = h1b[m2], wc = h1c[m2], wd = h1d[m2];
        ua = fmaf(bfu_lo(wu), w1l, ua); ua = fmaf(bfu_hi(wu), w1h, ua);
        pa = fmaf(bfu_lo(wp), w1l, pa); pa = fmaf(bfu_hi(wp), w1h, pa);
        a0 = fmaf(bfu_lo(wa), w1l, a0); a0 = fmaf(bfu_hi(wa), w1h, a0);
        a1 = fmaf(bfu_lo(wb), w1l, a1); a1 = fmaf(bfu_hi(wb), w1h, a1);
        a2 = fmaf(bfu_lo(wc), w1l, a2); a2 = fmaf(bfu_hi(wc), w1h, a2);
        a3 = fmaf(bfu_lo(wd), w1l, a3); a3 = fmaf(bfu_hi(wd), w1h, a3);
    }
    #pragma unroll 4
    for (int m = 0; m < 128; m++){
        float w2 = lw[128 + m];
        ua = fmaf(h2u[m], w2, ua);
        pa = fmaf(h2p[m], w2, pa);
        a0 = fmaf(h2a[m], w2, a0);
        a1 = fmaf(h2b[m], w2, a1);
        a2 = fmaf(h2cc[m], w2, a2);
        a3 = fmaf(h2d[m], w2, a3);
    }
    float dp = ua * pa;
    float dn = ua * (a0 + a1 + a2 + a3);
    #pragma unroll
    for (int off = 32; off > 0; off >>= 1){
        dp += __shfl_down(dp, off, 64);
        dn += __shfl_down(dn, off, 64);
    }
    __shared__ float red[4];
    if ((j & 63) == 0){ red[(j >> 6) * 2] = dp; red[(j >> 6) * 2 + 1] = dn; }
    __syncthreads();
    if (j == 0){
        float P = red[0] + red[2];
        float N = red[1] + red[3];
        float v = 0.25f * N - P + 1.0f;
        bloss[b] = fminf(fmaxf(v, 1e-6f), 1e4f);
    }
}

__global__ __launch_bounds__(1024)
void loss_kernel(const float* __restrict__ bloss, float* __restrict__ out)
{
    const int t = threadIdx.x;
    float v = bloss[t];
    #pragma unroll
    for (int off = 32; off > 0; off >>= 1) v += __shfl_down(v, off, 64);
    __shared__ float red[16];
    if ((t & 63) == 0) red[t >> 6] = v;
    __syncthreads();
    if (t == 0){
        float s = 0.f;
        #pragma unroll
        for (int i = 0; i < 16; i++) s += red[i];
        out[0] = s;
    }
}

extern "C" void kernel_launch(void* const* d_in, const int* in_sizes, int n_in,
                              void* d_out, int out_size, void* d_ws, size_t ws_size,
                              hipStream_t stream)
{
    const float* word_emb  = (const float*)d_in[0];
    const float* other_pos = (const float*)d_in[1];
    const float* user_pos  = (const float*)d_in[2];
    const float* item_pos  = (const float*)d_in[3];
    const float* w_ih0 = (const float*)d_in[4];
    const float* w_hh0 = (const float*)d_in[5];
    const float* b_ih0 = (const float*)d_in[6];
    const float* b_hh0 = (const float*)d_in[7];
    const float* w_ih1 = (const float*)d_in[8];
    const float* w_hh1 = (const float*)d_in[9];
    const float* b_ih1 = (const float*)d_in[10];
    const float* b_hh1 = (const float*)d_in[11];
    const float* conv1_w = (const float*)d_in[12];
    const float* conv1_b = (const float*)d_in[13];
    const float* conv2_w = (const float*)d_in[14];
    const float* conv2_b = (const float*)d_in[15];
    const float* lin_w   = (const float*)d_in[16];
    const float* lin_b   = (const float*)d_in[17];
    const int* adj_row = (const int*)d_in[18];
    const int* adj_col = (const int*)d_in[19];
    const float* adj_vals = (const float*)d_in[20];
    const int* lookup   = (const int*)d_in[21];
    const int* user     = (const int*)d_in[22];
    const int* pos_item = (const int*)d_in[23];
    const int* neg_item = (const int*)d_in[24];

    float* ws = (float*)d_ws;

    uint32_t* h1bf = (uint32_t*)ws;                        // [N*64]  4,608,000 w
    uint32_t* zbf  = h1bf + 4608000;                       // [N*64]  4,608,000 w
    float*    h2c  = (float*)(zbf + 4608000);              // [NSLOT*128] 786,432 w
    uint32_t* abf  = (uint32_t*)(h2c + 786432);            // [N*32]  2,304,000 w
    uint32_t* ebf  = abf + 2304000;                        // [(V+1)*32] 1,600,032 w
    uint32_t* y1bf = ebf + 1600032;                        // [N*32]  2,304,000 w (packed bf16)
    float*    bloss = (float*)(y1bf + 2304000);            // [1024]
    int* rowptr = (int*)(bloss + 1088);                    // [NNODES+1]
    int* cursor = rowptr + 72004;
    int* deg    = cursor + 72004;
    int* bsum   = deg + 72004;                             // [NSB]
    int2* cv    = (int2*)(bsum + 128);                     // [NEDGE]

    (void)hipMemsetAsync(deg, 0, NNODES * sizeof(int), stream);

    prep_kernel<<<EB_BLKS + DEG_BLKS, 256, 0, stream>>>(word_emb, ebf, adj_row, deg);

    scan1_kernel<<<NSB, 1024, 0, stream>>>(deg, rowptr, bsum);
    scan3_kernel<<<NSB, 1024, 0, stream>>>(deg, rowptr, bsum, cursor);
    scat_kernel<<<(NEDGE + 255) / 256, 256, 0, stream>>>(adj_row, adj_col, adj_vals, cursor, cv);

    gru_kernel<<<NNODES / 64, 512, 0, stream>>>(
        ebf, lookup, w_ih0, w_hh0, b_ih0, b_hh0,
        w_ih1, w_hh1, b_ih1, b_hh1,
        other_pos, user_pos, item_pos, abf);

    spmm64_csr<<<NNODES / 4, 256, 0, stream>>>(rowptr, cv, (const ushort*)abf, (ushort*)y1bf);

    gemm12_mfma<<<NNODES / 64, 256, 0, stream>>>(y1bf, conv1_w, conv1_b, conv2_w, h1bf, zbf);

    spmm128_slots<<<NSLOT / 4, 256, 0, stream>>>(rowptr, cv, zbf, conv2_b,
                                                 user, pos_item, neg_item, h2c);

    score_kernel<<<BSZ, 128, 0, stream>>>(h1bf, h2c, lin_w, lin_b, user, pos_item, neg_item, bloss);

    loss_kernel<<<1, 1024, 0, stream>>>(bloss, (float*)d_out);
}

// Round 15
// 463.026 us; speedup vs baseline: 1.2735x; 1.1378x over previous
//
#include <hip/hip_runtime.h>
#include <hip/hip_bf16.h>
#include <stdint.h>

#define NNODES 72000
#define NBO 2000
#define NBU 20000
#define NBI 50000
#define NEDGE 1152000
#define VOCAB 50000
#define TSEQ 20
#define BSZ 1024
#define KNEG 4
#define NSB 71     // scan blocks: 71*1024 >= 72000
#define NSLOT (2 * BSZ + KNEG * BSZ)   // 6144 scored slots: user | pos | neg
#define EB_ELEM ((VOCAB + 1) * 32)     // 1,600,032 packed words
#define EB_BLKS ((EB_ELEM + 255) / 256)
#define DEG_BLKS ((NEDGE + 255) / 256)

typedef __attribute__((ext_vector_type(8))) short bf16x8;
typedef __attribute__((ext_vector_type(4))) float f32x4;

__device__ __forceinline__ float rcp_fast(float x){ return __builtin_amdgcn_rcpf(x); }
__device__ __forceinline__ float sigmoidf_(float x){ return rcp_fast(1.f + __expf(-x)); }
__device__ __forceinline__ float tanhf_(float x){
    float xx = fminf(fmaxf(x, -15.f), 15.f);
    float e = __expf(-2.f * xx);
    return (1.f - e) * rcp_fast(1.f + e);
}
__device__ __forceinline__ uint32_t f2bf_rne(float f){
    uint32_t u = __float_as_uint(f);
    return (u + 0x7fffu + ((u >> 16) & 1u)) >> 16;
}
// HW packed convert: 2 fp32 -> 2 bf16 (v_cvt_pk_bf16_f32); memcpy = reg move
__device__ __forceinline__ uint32_t pkbf(float lo, float hi){
    __hip_bfloat162 h = __float22bfloat162_rn(make_float2(lo, hi));
    uint32_t r;
    __builtin_memcpy(&r, &h, 4);
    return r;
}
__device__ __forceinline__ float bfu_lo(uint32_t p){ return __uint_as_float(p << 16); }
__device__ __forceinline__ float bfu_hi(uint32_t p){ return __uint_as_float(p & 0xffff0000u); }

__device__ __forceinline__ f32x4 mfma16(bf16x8 a, bf16x8 b, f32x4 c){
    return __builtin_amdgcn_mfma_f32_16x16x32_bf16(a, b, c, 0, 0, 0);
}

// XOR swizzle for 128B-row LDS tiles (16B slots spread per 8-row stripe)
__device__ __forceinline__ int swz(int b){ return b ^ (((b >> 7) & 7) << 4); }
// XOR swizzle for 256B-row tiles
__device__ __forceinline__ int swzE(int b){ return b ^ (((b >> 8) & 7) << 4); }

// ---------------- MFMA GRU ----------------
// r14: 256 threads = 4 waves, 32 nodes/block, 4 blocks/CU (VGPR-limited, NOT
// launch-bounds-capped: (256,2) keeps the 256-VGPR ceiling so the proven
// ~120-VGPR allocation is preserved -- r7's failure was (256,4)'s 64-VGPR cap).
// More independent barrier groups/CU (4 vs 2) to hide the per-phase LDS
// round-trip. Per-thread code identical to r8 with ctb=0.

__device__ __forceinline__ void gru_layer_step(
    const char* __restrict__ xsrc, const char* __restrict__ hsrc,
    const bf16x8 (&wih)[3][2], const bf16x8 (&whh)[3][2],
    const f32x4& rb, const f32x4& zb, const f32x4& ib, const f32x4& hb,
    f32x4 (&hreg)[2], int lane)
{
    f32x4 ar[2], az[2], ain[2], ahn[2];
    #pragma unroll
    for (int c = 0; c < 2; c++){ ar[c] = rb; az[c] = zb; ain[c] = ib; ahn[c] = hb; }
    const int lrow = (lane & 15) * 128 + (lane >> 4) * 16;
    __builtin_amdgcn_s_setprio(1);
    #pragma unroll
    for (int kf = 0; kf < 2; kf++){
        #pragma unroll
        for (int c = 0; c < 2; c++){
            int byte = c * 2048 + kf * 64 + lrow;
            bf16x8 bx = *(const bf16x8*)(xsrc + swz(byte));
            bf16x8 bh = *(const bf16x8*)(hsrc + swz(byte));
            ar[c]  = mfma16(wih[0][kf], bx, ar[c]);
            ar[c]  = mfma16(whh[0][kf], bh, ar[c]);
            az[c]  = mfma16(wih[1][kf], bx, az[c]);
            az[c]  = mfma16(whh[1][kf], bh, az[c]);
            ain[c] = mfma16(wih[2][kf], bx, ain[c]);
            ahn[c] = mfma16(whh[2][kf], bh, ahn[c]);
        }
    }
    __builtin_amdgcn_s_setprio(0);
    #pragma unroll
    for (int c = 0; c < 2; c++){
        #pragma unroll
        for (int r4 = 0; r4 < 4; r4++){
            float rg = sigmoidf_(ar[c][r4]);
            float zg = sigmoidf_(az[c][r4]);
            float ng = tanhf_(fmaf(rg, ahn[c][r4], ain[c][r4]));
            hreg[c][r4] = fmaf(zg, hreg[c][r4] - ng, ng);
        }
    }
}

__device__ __forceinline__ void write_h(char* __restrict__ dst,
                                        const f32x4 (&hreg)[2], int w4, int lane)
{
    #pragma unroll
    for (int c = 0; c < 2; c++){
        uint32_t p0 = pkbf(hreg[c][0], hreg[c][1]);
        uint32_t p1 = pkbf(hreg[c][2], hreg[c][3]);
        int byte = (c * 16 + (lane & 15)) * 128 + w4 * 32 + (lane >> 4) * 8;
        *(uint2*)(dst + swz(byte)) = make_uint2(p0, p1);
    }
}

__global__ __launch_bounds__(256, 2)
void gru_kernel(const uint32_t* __restrict__ ebf,
                const int* __restrict__ lookup,
                const float* __restrict__ w_ih0, const float* __restrict__ w_hh0,
                const float* __restrict__ b_ih0, const float* __restrict__ b_hh0,
                const float* __restrict__ w_ih1, const float* __restrict__ w_hh1,
                const float* __restrict__ b_ih1, const float* __restrict__ b_hh1,
                const float* __restrict__ other_pos, const float* __restrict__ user_pos,
                const float* __restrict__ item_pos,
                uint32_t* __restrict__ abf)
{
    __shared__ __align__(16) char xbuf[2][4096];   // [32 nodes][128B bf16], swz
    __shared__ __align__(16) char h0buf[2][4096];
    __shared__ __align__(16) char h1buf[2][4096];

    const int tid  = threadIdx.x;
    const int lane = tid & 63;
    const int w4   = tid >> 6;          // wave = gate group 0..3

    const float* mats[4] = { w_ih0, w_hh0, w_ih1, w_hh1 };
    bf16x8 wf[4][3][2];
    #pragma unroll
    for (int m = 0; m < 4; m++){
        #pragma unroll
        for (int g = 0; g < 3; g++){
            #pragma unroll
            for (int kf = 0; kf < 2; kf++){
                int row = (g * 4 + w4) * 16 + (lane & 15);
                int k0  = kf * 32 + (lane >> 4) * 8;
                const float* p = mats[m] + row * 64 + k0;
                float4 a = *(const float4*)p;
                float4 b = *(const float4*)(p + 4);
                bf16x8 f;
                f[0] = (short)f2bf_rne(a.x); f[1] = (short)f2bf_rne(a.y);
                f[2] = (short)f2bf_rne(a.z); f[3] = (short)f2bf_rne(a.w);
                f[4] = (short)f2bf_rne(b.x); f[5] = (short)f2bf_rne(b.y);
                f[6] = (short)f2bf_rne(b.z); f[7] = (short)f2bf_rne(b.w);
                wf[m][g][kf] = f;
            }
        }
    }

    const int bofs = w4 * 16 + (lane >> 4) * 4;
    f32x4 rb0, zb0, ib0, hb0, rb1, zb1, ib1, hb1;
    #pragma unroll
    for (int r4 = 0; r4 < 4; r4++){
        rb0[r4] = b_ih0[bofs + r4]       + b_hh0[bofs + r4];
        zb0[r4] = b_ih0[64 + bofs + r4]  + b_hh0[64 + bofs + r4];
        ib0[r4] = b_ih0[128 + bofs + r4];
        hb0[r4] = b_hh0[128 + bofs + r4];
        rb1[r4] = b_ih1[bofs + r4]       + b_hh1[bofs + r4];
        zb1[r4] = b_ih1[64 + bofs + r4]  + b_hh1[64 + bofs + r4];
        ib1[r4] = b_ih1[128 + bofs + r4];
        hb1[r4] = b_hh1[128 + bofs + r4];
    }

    {
        uint4 z4 = make_uint4(0, 0, 0, 0);
        ((uint4*)h0buf[0])[tid] = z4;
        ((uint4*)h1buf[0])[tid] = z4;
    }
    const int pnl = tid >> 3, pdg = tid & 7;   // 8 threads stage one node's 128B row
    const long nodeP = (long)blockIdx.x * 32 + pnl;
    const int sbyte = pnl * 128 + pdg * 16;
    {
        int idx = lookup[nodeP * TSEQ + 0];
        uint4 a = ((const uint4*)(ebf + (size_t)idx * 32))[pdg];
        *(uint4*)(xbuf[0] + swz(sbyte)) = a;
    }
    __syncthreads();

    f32x4 h0reg[2], h1reg[2];
    #pragma unroll
    for (int c = 0; c < 2; c++){
        #pragma unroll
        for (int r4 = 0; r4 < 4; r4++){ h0reg[c][r4] = 0.f; h1reg[c][r4] = 0.f; }
    }

    for (int t = 0; t < TSEQ; t++){
        const int p = t & 1, q = p ^ 1;
        const bool pf = (t + 1 < TSEQ);
        uint4 xa;
        if (pf){
            int idx = lookup[nodeP * TSEQ + t + 1];
            xa = ((const uint4*)(ebf + (size_t)idx * 32))[pdg];
        }
        gru_layer_step(xbuf[p], h0buf[p], wf[0], wf[1], rb0, zb0, ib0, hb0, h0reg, lane);
        write_h(h0buf[q], h0reg, w4, lane);
        __syncthreads();
        gru_layer_step(h0buf[q], h1buf[p], wf[2], wf[3], rb1, zb1, ib1, hb1, h1reg, lane);
        write_h(h1buf[q], h1reg, w4, lane);
        if (pf) *(uint4*)(xbuf[q] + swz(sbyte)) = xa;
        __syncthreads();
    }

    // epilogue: stage fp32 h1 (32 nodes x 256B = 8KB across xbuf)
    float* xstage = (float*)xbuf;
    #pragma unroll
    for (int c = 0; c < 2; c++){
        int nl = c * 16 + (lane & 15);
        int byte = nl * 256 + w4 * 64 + (lane >> 4) * 16;
        *(float4*)((char*)xstage + swzE(byte)) =
            make_float4(h1reg[c][0], h1reg[c][1], h1reg[c][2], h1reg[c][3]);
    }
    __syncthreads();
    {
        long node = nodeP;
        const float* pp; long off;
        if (node < NBO)            { pp = other_pos; off = node; }
        else if (node < NBO + NBU) { pp = user_pos;  off = node - NBO; }
        else                       { pp = item_pos;  off = node - NBO - NBU; }
        const float* pr = pp + off * 64 + pdg * 8;
        float4 pa = *(const float4*)pr;
        float4 pb = *(const float4*)(pr + 4);
        int byte = pnl * 256 + pdg * 32;
        float4 ha = *(float4*)((char*)xstage + swzE(byte));
        float4 hb2 = *(float4*)((char*)xstage + swzE(byte + 16));
        uint4 ov;
        ov.x = pkbf(pa.x + ha.x, pa.y + ha.y);
        ov.y = pkbf(pa.z + ha.z, pa.w + ha.w);
        ov.z = pkbf(pb.x + hb2.x, pb.y + hb2.y);
        ov.w = pkbf(pb.z + hb2.z, pb.w + hb2.w);
        ((uint4*)abf)[node * 8 + pdg] = ov;
    }
}

// ---------------- prep: emb2bf (blocks [0,EB_BLKS)) + deg atomics (rest) ----------------
__global__ __launch_bounds__(256)
void prep_kernel(const float* __restrict__ we, uint32_t* __restrict__ ebf,
                 const int* __restrict__ row, int* __restrict__ deg)
{
    if (blockIdx.x < EB_BLKS){
        size_t i = (size_t)blockIdx.x * 256 + threadIdx.x;
        if (i < (size_t)EB_ELEM){
            float2 v = ((const float2*)we)[i];
            ebf[i] = pkbf(v.x, v.y);
        }
    } else {
        int e = (blockIdx.x - EB_BLKS) * 256 + threadIdx.x;
        if (e < NEDGE) atomicAdd(&deg[row[e]], 1);
    }
}

// ---------------- CSR build ----------------
__global__ __launch_bounds__(1024)
void scan1_kernel(const int* __restrict__ deg, int* __restrict__ rowptr, int* __restrict__ bsum)
{
    __shared__ int wsum[16];
    const int tid = threadIdx.x, lane = tid & 63, w = tid >> 6;
    const int i = blockIdx.x * 1024 + tid;
    int v = (i < NNODES) ? deg[i] : 0;
    int s = v;
    #pragma unroll
    for (int o = 1; o < 64; o <<= 1){
        int t = __shfl_up(s, o, 64);
        if (lane >= o) s += t;
    }
    if (lane == 63) wsum[w] = s;
    __syncthreads();
    if (w == 0){
        int t = (lane < 16) ? wsum[lane] : 0;
        #pragma unroll
        for (int o = 1; o < 16; o <<= 1){
            int u = __shfl_up(t, o, 64);
            if (lane >= o) t += u;
        }
        if (lane < 16) wsum[lane] = t;
    }
    __syncthreads();
    int incl = s + ((w > 0) ? wsum[w - 1] : 0);
    if (i < NNODES) rowptr[i + 1] = incl;
    if (tid == 0) bsum[blockIdx.x] = wsum[15];
}

// scan3 with inline block-offset reduce (replaces scan2)
__global__ __launch_bounds__(1024)
void scan3_kernel(const int* __restrict__ deg, int* __restrict__ rowptr,
                  const int* __restrict__ bsum, int* __restrict__ cursor)
{
    __shared__ int boff_sh;
    const int tid = threadIdx.x;
    if (tid < 64){
        int v = 0;
        for (int k = tid; k < blockIdx.x; k += 64) v += bsum[k];
        #pragma unroll
        for (int o = 32; o > 0; o >>= 1) v += __shfl_down(v, o, 64);
        if (tid == 0) boff_sh = v;
    }
    __syncthreads();
    const int i = blockIdx.x * 1024 + tid;
    if (i < NNODES){
        int r = rowptr[i + 1] + boff_sh;
        rowptr[i + 1] = r;
        cursor[i] = r - deg[i];
    }
    if (i == 0) rowptr[0] = 0;
}

__global__ __launch_bounds__(256)
void scat_kernel(const int* __restrict__ row, const int* __restrict__ col,
                 const float* __restrict__ vals, int* __restrict__ cursor,
                 int2* __restrict__ cv)
{
    int e = blockIdx.x * 256 + threadIdx.x;
    if (e < NEDGE){
        int p = atomicAdd(&cursor[row[e]], 1);
        cv[p] = make_int2(col[e], __float_as_int(vals[e]));
    }
}

// ---------------- CSR spmm64: one wave per row, high TLP, writes bf16 y1 ----------------
__global__ __launch_bounds__(256)
void spmm64_csr(const int* __restrict__ rowptr, const int2* __restrict__ cv,
                const ushort* __restrict__ xb, ushort* __restrict__ y1bf)
{
    const int r = blockIdx.x * 4 + (threadIdx.x >> 6);
    const int lane = threadIdx.x & 63;
    const int e0 = rowptr[r], e1 = rowptr[r + 1];
    float acc = 0.f;
    int e = e0;
    for (; e + 7 < e1; e += 8){
        int2 a[8];
        #pragma unroll
        for (int q = 0; q < 8; q++) a[q] = cv[e + q];
        float x[8];
        #pragma unroll
        for (int q = 0; q < 8; q++)
            x[q] = __uint_as_float((uint32_t)xb[(size_t)a[q].x * 64 + lane] << 16);
        #pragma unroll
        for (int q = 0; q < 8; q++) acc = fmaf(__int_as_float(a[q].y), x[q], acc);
    }
    for (; e + 3 < e1; e += 4){
        int2 a0 = cv[e], a1 = cv[e + 1], a2 = cv[e + 2], a3 = cv[e + 3];
        float x0 = __uint_as_float((uint32_t)xb[(size_t)a0.x * 64 + lane] << 16);
        float x1 = __uint_as_float((uint32_t)xb[(size_t)a1.x * 64 + lane] << 16);
        float x2 = __uint_as_float((uint32_t)xb[(size_t)a2.x * 64 + lane] << 16);
        float x3 = __uint_as_float((uint32_t)xb[(size_t)a3.x * 64 + lane] << 16);
        acc = fmaf(__int_as_float(a0.y), x0, acc);
        acc = fmaf(__int_as_float(a1.y), x1, acc);
        acc = fmaf(__int_as_float(a2.y), x2, acc);
        acc = fmaf(__int_as_float(a3.y), x3, acc);
    }
    for (; e < e1; e++){
        int2 a = cv[e];
        acc = fmaf(__int_as_float(a.y),
                   __uint_as_float((uint32_t)xb[(size_t)a.x * 64 + lane] << 16), acc);
    }
    y1bf[(size_t)r * 64 + lane] = (ushort)f2bf_rne(acc);
}

// h2c[slot] = bias + sum_e A[node(slot),c] * z2[c]  -- only 6144 scored slots
__global__ __launch_bounds__(256)
void spmm128_slots(const int* __restrict__ rowptr, const int2* __restrict__ cv,
                   const uint32_t* __restrict__ zb, const float* __restrict__ b2,
                   const int* __restrict__ user, const int* __restrict__ pos_item,
                   const int* __restrict__ neg_item, float* __restrict__ h2c)
{
    const int slot = blockIdx.x * 4 + (threadIdx.x >> 6);
    const int lane = threadIdx.x & 63;
    int r;
    if (slot < BSZ)            r = NBO + user[slot];
    else if (slot < 2 * BSZ)   r = NBO + NBU + pos_item[slot - BSZ];
    else                       r = NBO + NBU + neg_item[slot - 2 * BSZ];
    const int e0 = rowptr[r], e1 = rowptr[r + 1];
    float2 acc = make_float2(b2[2 * lane], b2[2 * lane + 1]);
    int e = e0;
    for (; e + 1 < e1; e += 2){
        int2 a0 = cv[e], a1 = cv[e + 1];
        uint32_t z0 = zb[(size_t)a0.x * 64 + lane];
        uint32_t z1 = zb[(size_t)a1.x * 64 + lane];
        float v0 = __int_as_float(a0.y), v1 = __int_as_float(a1.y);
        acc.x = fmaf(v0, bfu_lo(z0), acc.x);
        acc.y = fmaf(v0, bfu_hi(z0), acc.y);
        acc.x = fmaf(v1, bfu_lo(z1), acc.x);
        acc.y = fmaf(v1, bfu_hi(z1), acc.y);
    }
    if (e < e1){
        int2 a = cv[e];
        uint32_t z0 = zb[(size_t)a.x * 64 + lane];
        float v = __int_as_float(a.y);
        acc.x = fmaf(v, bfu_lo(z0), acc.x);
        acc.y = fmaf(v, bfu_hi(z0), acc.y);
    }
    *(float2*)(h2c + (size_t)slot * 128 + 2 * lane) = acc;
}

// ---- fused dense: h1 = y1@W1+b1 (write bf16), z2 = h1@W2 (write bf16) ----
__global__ __launch_bounds__(256, 2)
void gemm12_mfma(const uint32_t* __restrict__ y1bf,
                 const float* __restrict__ W1, const float* __restrict__ b1,
                 const float* __restrict__ W2,
                 uint32_t* __restrict__ h1bf, uint32_t* __restrict__ zbf)
{
    __shared__ __align__(16) char ybuf[8192];    // [64 nodes][128B bf16], swz
    __shared__ __align__(16) char hbuf[16384];   // [64 nodes][256B bf16], swzE
    const int tid = threadIdx.x, lane = tid & 63, w4 = tid >> 6;

    bf16x8 af1[2][2], af2[2][4];
    #pragma unroll
    for (int jt = 0; jt < 2; jt++){
        int jj = w4 * 32 + jt * 16 + (lane & 15);
        #pragma unroll
        for (int kf = 0; kf < 2; kf++){
            int k0 = kf * 32 + (lane >> 4) * 8;
            bf16x8 f;
            #pragma unroll
            for (int i = 0; i < 8; i++) f[i] = (short)f2bf_rne(W1[(size_t)(k0 + i) * 128 + jj]);
            af1[jt][kf] = f;
        }
        #pragma unroll
        for (int kf = 0; kf < 4; kf++){
            int k0 = kf * 32 + (lane >> 4) * 8;
            bf16x8 f;
            #pragma unroll
            for (int i = 0; i < 8; i++) f[i] = (short)f2bf_rne(W2[(size_t)(k0 + i) * 128 + jj]);
            af2[jt][kf] = f;
        }
    }
    float b1v[2][4];
    #pragma unroll
    for (int jt = 0; jt < 2; jt++)
        #pragma unroll
        for (int r4 = 0; r4 < 4; r4++)
            b1v[jt][r4] = b1[w4 * 32 + jt * 16 + (lane >> 4) * 4 + r4];

    // stage y1 tile (already bf16): 4 threads/node, 32B each
    const int snl = tid >> 2, sq = tid & 3;
    {
        const uint32_t* yr = y1bf + ((size_t)blockIdx.x * 64 + snl) * 32 + sq * 8;
        uint4 p0 = *(const uint4*)yr;
        uint4 p1 = *(const uint4*)(yr + 4);
        int base = snl * 128 + sq * 32;
        *(uint4*)(ybuf + swz(base))      = p0;
        *(uint4*)(ybuf + swz(base + 16)) = p1;
    }
    __syncthreads();

    // pass 1: h1 = y1 @ W1 + b1
    f32x4 acc[2][4];
    #pragma unroll
    for (int jt = 0; jt < 2; jt++)
        #pragma unroll
        for (int ct = 0; ct < 4; ct++)
            #pragma unroll
            for (int r4 = 0; r4 < 4; r4++) acc[jt][ct][r4] = b1v[jt][r4];
    {
        const int lrow = (lane & 15) * 128 + (lane >> 4) * 16;
        __builtin_amdgcn_s_setprio(1);
        #pragma unroll
        for (int kf = 0; kf < 2; kf++){
            #pragma unroll
            for (int ct = 0; ct < 4; ct++){
                int byte = ct * 2048 + kf * 64 + lrow;
                bf16x8 bfr = *(const bf16x8*)(ybuf + swz(byte));
                acc[0][ct] = mfma16(af1[0][kf], bfr, acc[0][ct]);
                acc[1][ct] = mfma16(af1[1][kf], bfr, acc[1][ct]);
            }
        }
        __builtin_amdgcn_s_setprio(0);
    }
    // stage h1 bf16 into hbuf [node][256B] swzE
    #pragma unroll
    for (int jt = 0; jt < 2; jt++){
        #pragma unroll
        for (int ct = 0; ct < 4; ct++){
            int node = ct * 16 + (lane & 15);
            int j2 = (w4 * 32 + jt * 16 + (lane >> 4) * 4) >> 1;
            uint32_t p0 = pkbf(acc[jt][ct][0], acc[jt][ct][1]);
            uint32_t p1 = pkbf(acc[jt][ct][2], acc[jt][ct][3]);
            *(uint2*)(hbuf + swzE(node * 256 + j2 * 4)) = make_uint2(p0, p1);
        }
    }
    __syncthreads();

    // global h1 write (coalesced) + pass 2 MFMA reads (both read hbuf)
    {
        uint32_t* dst = h1bf + ((size_t)blockIdx.x * 64 + snl) * 64 + sq * 16;
        #pragma unroll
        for (int q = 0; q < 4; q++)
            *(uint4*)(dst + q * 4) = *(uint4*)(hbuf + swzE(snl * 256 + sq * 64 + q * 16));
    }
    f32x4 acc2[2][4];
    #pragma unroll
    for (int jt = 0; jt < 2; jt++)
        #pragma unroll
        for (int ct = 0; ct < 4; ct++)
            #pragma unroll
            for (int r4 = 0; r4 < 4; r4++) acc2[jt][ct][r4] = 0.f;
    {
        const int lrow = (lane & 15) * 256 + (lane >> 4) * 16;
        __builtin_amdgcn_s_setprio(1);
        #pragma unroll
        for (int kf = 0; kf < 4; kf++){
            #pragma unroll
            for (int ct = 0; ct < 4; ct++){
                int byte = ct * 4096 + kf * 64 + lrow;
                bf16x8 bfr = *(const bf16x8*)(hbuf + swzE(byte));
                acc2[0][ct] = mfma16(af2[0][kf], bfr, acc2[0][ct]);
                acc2[1][ct] = mfma16(af2[1][kf], bfr, acc2[1][ct]);
            }
        }
        __builtin_amdgcn_s_setprio(0);
    }
    __syncthreads();   // all hbuf reads done before z-stage overwrites

    #pragma unroll
    for (int jt = 0; jt < 2; jt++){
        #pragma unroll
        for (int ct = 0; ct < 4; ct++){
            int node = ct * 16 + (lane & 15);
            int j2 = (w4 * 32 + jt * 16 + (lane >> 4) * 4) >> 1;
            uint32_t p0 = pkbf(acc2[jt][ct][0], acc2[jt][ct][1]);
            uint32_t p1 = pkbf(acc2[jt][ct][2], acc2[jt][ct][3]);
            *(uint2*)(hbuf + swzE(node * 256 + j2 * 4)) = make_uint2(p0, p1);
        }
    }
    __syncthreads();
    {
        uint32_t* dst = zbf + ((size_t)blockIdx.x * 64 + snl) * 64 + sq * 16;
        #pragma unroll
        for (int q = 0; q < 4; q++)
            *(uint4*)(dst + q * 4) = *(uint4*)(hbuf + swzE(snl * 256 + sq * 64 + q * 16));
    }
}

// ---------------- merged scoring: one block per b handles user/pos/4 negs ----------------
__global__ __launch_bounds__(128)
void score_kernel(const uint32_t* __restrict__ h1bf, const float* __restrict__ h2c,
                  const float* __restrict__ lin_w, const float* __restrict__ lin_b,
                  const int* __restrict__ user, const int* __restrict__ pos_item,
                  const int* __restrict__ neg_item, float* __restrict__ bloss)
{
    const int b = blockIdx.x, j = threadIdx.x;
    const int un = NBO + user[b];
    const int pn = NBO + NBU + pos_item[b];
    const int n0 = NBO + NBU + neg_item[b];
    const int n1 = NBO + NBU + neg_item[BSZ + b];
    const int n2 = NBO + NBU + neg_item[2 * BSZ + b];
    const int n3 = NBO + NBU + neg_item[3 * BSZ + b];
    const float* lw = lin_w + j * 256;
    const uint32_t* h1u = h1bf + (size_t)un * 64;  const float* h2u = h2c + (size_t)b * 128;
    const uint32_t* h1p = h1bf + (size_t)pn * 64;  const float* h2p = h2c + (size_t)(BSZ + b) * 128;
    const uint32_t* h1a = h1bf + (size_t)n0 * 64;  const float* h2a = h2c + (size_t)(2 * BSZ + b) * 128;
    const uint32_t* h1b = h1bf + (size_t)n1 * 64;  const float* h2b = h2c + (size_t)(3 * BSZ + b) * 128;
    const uint32_t* h1c = h1bf + (size_t)n2 * 64;  const float* h2cc = h2c + (size_t)(4 * BSZ + b) * 128;
    const uint32_t* h1d = h1bf + (size_t)n3 * 64;  const float* h2d = h2c + (size_t)(5 * BSZ + b) * 128;
    float lb = lin_b[j];
    float ua = lb, pa = lb, a0 = lb, a1 = lb, a2 = lb, a3 = lb;
    #pragma unroll 4
    for (int m2 = 0; m2 < 64; m2++){
        float w1l = lw[2 * m2], w1h = lw[2 * m2 + 1];
        uint32_t wu = h1u[m2], wp = h1p[m2], wa = h1a[m2], wb = h1b[m2], wc = h1c[m2], wd = h1d[m2];
        ua = fmaf(bfu_lo(wu), w1l, ua); ua = fmaf(bfu_hi(wu), w1h, ua);
        pa = fmaf(bfu_lo(wp), w1l, pa); pa = fmaf(bfu_hi(wp), w1h, pa);
        a0 = fmaf(bfu_lo(wa), w1l, a0); a0 = fmaf(bfu_hi(wa), w1h, a0);
        a1 = fmaf(bfu_lo(wb), w1l, a1); a1 = fmaf(bfu_hi(wb), w1h, a1);
        a2 = fmaf(bfu_lo(wc), w1l, a2); a2 = fmaf(bfu_hi(wc), w1h, a2);
        a3 = fmaf(bfu_lo(wd), w1l, a3); a3 = fmaf(bfu_hi(wd), w1h, a3);
    }
    #pragma unroll 4
    for (int m = 0; m < 128; m++){
        float w2 = lw[128 + m];
        ua = fmaf(h2u[m], w2, ua);
        pa = fmaf(h2p[m], w2, pa);
        a0 = fmaf(h2a[m], w2, a0);
        a1 = fmaf(h2b[m], w2, a1);
        a2 = fmaf(h2cc[m], w2, a2);
        a3 = fmaf(h2d[m], w2, a3);
    }
    float dp = ua * pa;
    float dn = ua * (a0 + a1 + a2 + a3);
    #pragma unroll
    for (int off = 32; off > 0; off >>= 1){
        dp += __shfl_down(dp, off, 64);
        dn += __shfl_down(dn, off, 64);
    }
    __shared__ float red[4];
    if ((j & 63) == 0){ red[(j >> 6) * 2] = dp; red[(j >> 6) * 2 + 1] = dn; }
    __syncthreads();
    if (j == 0){
        float P = red[0] + red[2];
        float N = red[1] + red[3];
        float v = 0.25f * N - P + 1.0f;
        bloss[b] = fminf(fmaxf(v, 1e-6f), 1e4f);
    }
}

__global__ __launch_bounds__(1024)
void loss_kernel(const float* __restrict__ bloss, float* __restrict__ out)
{
    const int t = threadIdx.x;
    float v = bloss[t];
    #pragma unroll
    for (int off = 32; off > 0; off >>= 1) v += __shfl_down(v, off, 64);
    __shared__ float red[16];
    if ((t & 63) == 0) red[t >> 6] = v;
    __syncthreads();
    if (t == 0){
        float s = 0.f;
        #pragma unroll
        for (int i = 0; i < 16; i++) s += red[i];
        out[0] = s;
    }
}

extern "C" void kernel_launch(void* const* d_in, const int* in_sizes, int n_in,
                              void* d_out, int out_size, void* d_ws, size_t ws_size,
                              hipStream_t stream)
{
    const float* word_emb  = (const float*)d_in[0];
    const float* other_pos = (const float*)d_in[1];
    const float* user_pos  = (const float*)d_in[2];
    const float* item_pos  = (const float*)d_in[3];
    const float* w_ih0 = (const float*)d_in[4];
    const float* w_hh0 = (const float*)d_in[5];
    const float* b_ih0 = (const float*)d_in[6];
    const float* b_hh0 = (const float*)d_in[7];
    const float* w_ih1 = (const float*)d_in[8];
    const float* w_hh1 = (const float*)d_in[9];
    const float* b_ih1 = (const float*)d_in[10];
    const float* b_hh1 = (const float*)d_in[11];
    const float* conv1_w = (const float*)d_in[12];
    const float* conv1_b = (const float*)d_in[13];
    const float* conv2_w = (const float*)d_in[14];
    const float* conv2_b = (const float*)d_in[15];
    const float* lin_w   = (const float*)d_in[16];
    const float* lin_b   = (const float*)d_in[17];
    const int* adj_row = (const int*)d_in[18];
    const int* adj_col = (const int*)d_in[19];
    const float* adj_vals = (const float*)d_in[20];
    const int* lookup   = (const int*)d_in[21];
    const int* user     = (const int*)d_in[22];
    const int* pos_item = (const int*)d_in[23];
    const int* neg_item = (const int*)d_in[24];

    float* ws = (float*)d_ws;

    uint32_t* h1bf = (uint32_t*)ws;                        // [N*64]  4,608,000 w
    uint32_t* zbf  = h1bf + 4608000;                       // [N*64]  4,608,000 w
    float*    h2c  = (float*)(zbf + 4608000);              // [NSLOT*128] 786,432 w
    uint32_t* abf  = (uint32_t*)(h2c + 786432);            // [N*32]  2,304,000 w
    uint32_t* ebf  = abf + 2304000;                        // [(V+1)*32] 1,600,032 w
    uint32_t* y1bf = ebf + 1600032;                        // [N*32]  2,304,000 w (packed bf16)
    float*    bloss = (float*)(y1bf + 2304000);            // [1024]
    int* rowptr = (int*)(bloss + 1088);                    // [NNODES+1]
    int* cursor = rowptr + 72004;
    int* deg    = cursor + 72004;
    int* bsum   = deg + 72004;                             // [NSB]
    int2* cv    = (int2*)(bsum + 128);                     // [NEDGE]

    (void)hipMemsetAsync(deg, 0, NNODES * sizeof(int), stream);

    prep_kernel<<<EB_BLKS + DEG_BLKS, 256, 0, stream>>>(word_emb, ebf, adj_row, deg);

    scan1_kernel<<<NSB, 1024, 0, stream>>>(deg, rowptr, bsum);
    scan3_kernel<<<NSB, 1024, 0, stream>>>(deg, rowptr, bsum, cursor);
    scat_kernel<<<(NEDGE + 255) / 256, 256, 0, stream>>>(adj_row, adj_col, adj_vals, cursor, cv);

    gru_kernel<<<NNODES / 32, 256, 0, stream>>>(
        ebf, lookup, w_ih0, w_hh0, b_ih0, b_hh0,
        w_ih1, w_hh1, b_ih1, b_hh1,
        other_pos, user_pos, item_pos, abf);

    spmm64_csr<<<NNODES / 4, 256, 0, stream>>>(rowptr, cv, (const ushort*)abf, (ushort*)y1bf);

    gemm12_mfma<<<NNODES / 64, 256, 0, stream>>>(y1bf, conv1_w, conv1_b, conv2_w, h1bf, zbf);

    spmm128_slots<<<NSLOT / 4, 256, 0, stream>>>(rowptr, cv, zbf, conv2_b,
                                                 user, pos_item, neg_item, h2c);

    score_kernel<<<BSZ, 128, 0, stream>>>(h1bf, h2c, lin_w, lin_b, user, pos_item, neg_item, bloss);

    loss_kernel<<<1, 1024, 0, stream>>>(bloss, (float*)d_out);
}

// Round 16
// 417.986 us; speedup vs baseline: 1.4107x; 1.1078x over previous
//
#include <hip/hip_runtime.h>
#include <hip/hip_bf16.h>
#include <stdint.h>

#define NNODES 72000
#define NBO 2000
#define NBU 20000
#define NBI 50000
#define NEDGE 1152000
#define VOCAB 50000
#define TSEQ 20
#define BSZ 1024
#define KNEG 4
#define NSB 71     // scan blocks: 71*1024 >= 72000
#define NSLOT (2 * BSZ + KNEG * BSZ)   // 6144 scored slots: user | pos | neg
#define EB_ELEM ((VOCAB + 1) * 32)     // 1,600,032 packed words
#define EB_BLKS ((EB_ELEM + 255) / 256)
#define DEG_BLKS ((NEDGE + 255) / 256)
#define GRUB (NNODES / 32)             // 2250 gru blocks
#define SCAT_BLKS ((NEDGE + 255) / 256)

typedef __attribute__((ext_vector_type(8))) short bf16x8;
typedef __attribute__((ext_vector_type(4))) float f32x4;

__device__ __forceinline__ float rcp_fast(float x){ return __builtin_amdgcn_rcpf(x); }
__device__ __forceinline__ float sigmoidf_(float x){ return rcp_fast(1.f + __expf(-x)); }
__device__ __forceinline__ float tanhf_(float x){
    float xx = fminf(fmaxf(x, -15.f), 15.f);
    float e = __expf(-2.f * xx);
    return (1.f - e) * rcp_fast(1.f + e);
}
__device__ __forceinline__ uint32_t f2bf_rne(float f){
    uint32_t u = __float_as_uint(f);
    return (u + 0x7fffu + ((u >> 16) & 1u)) >> 16;
}
// HW packed convert: 2 fp32 -> 2 bf16 (v_cvt_pk_bf16_f32); memcpy = reg move
__device__ __forceinline__ uint32_t pkbf(float lo, float hi){
    __hip_bfloat162 h = __float22bfloat162_rn(make_float2(lo, hi));
    uint32_t r;
    __builtin_memcpy(&r, &h, 4);
    return r;
}
__device__ __forceinline__ float bfu_lo(uint32_t p){ return __uint_as_float(p << 16); }
__device__ __forceinline__ float bfu_hi(uint32_t p){ return __uint_as_float(p & 0xffff0000u); }

__device__ __forceinline__ f32x4 mfma16(bf16x8 a, bf16x8 b, f32x4 c){
    return __builtin_amdgcn_mfma_f32_16x16x32_bf16(a, b, c, 0, 0, 0);
}

// XOR swizzle for 128B-row LDS tiles (16B slots spread per 8-row stripe)
__device__ __forceinline__ int swz(int b){ return b ^ (((b >> 7) & 7) << 4); }
// XOR swizzle for 256B-row tiles
__device__ __forceinline__ int swzE(int b){ return b ^ (((b >> 8) & 7) << 4); }

// ---------------- MFMA GRU (r15 proven) + fused scat tail blocks ----------------

__device__ __forceinline__ void gru_layer_step(
    const char* __restrict__ xsrc, const char* __restrict__ hsrc,
    const bf16x8 (&wih)[3][2], const bf16x8 (&whh)[3][2],
    const f32x4& rb, const f32x4& zb, const f32x4& ib, const f32x4& hb,
    f32x4 (&hreg)[2], int lane)
{
    f32x4 ar[2], az[2], ain[2], ahn[2];
    #pragma unroll
    for (int c = 0; c < 2; c++){ ar[c] = rb; az[c] = zb; ain[c] = ib; ahn[c] = hb; }
    const int lrow = (lane & 15) * 128 + (lane >> 4) * 16;
    __builtin_amdgcn_s_setprio(1);
    #pragma unroll
    for (int kf = 0; kf < 2; kf++){
        #pragma unroll
        for (int c = 0; c < 2; c++){
            int byte = c * 2048 + kf * 64 + lrow;
            bf16x8 bx = *(const bf16x8*)(xsrc + swz(byte));
            bf16x8 bh = *(const bf16x8*)(hsrc + swz(byte));
            ar[c]  = mfma16(wih[0][kf], bx, ar[c]);
            ar[c]  = mfma16(whh[0][kf], bh, ar[c]);
            az[c]  = mfma16(wih[1][kf], bx, az[c]);
            az[c]  = mfma16(whh[1][kf], bh, az[c]);
            ain[c] = mfma16(wih[2][kf], bx, ain[c]);
            ahn[c] = mfma16(whh[2][kf], bh, ahn[c]);
        }
    }
    __builtin_amdgcn_s_setprio(0);
    #pragma unroll
    for (int c = 0; c < 2; c++){
        #pragma unroll
        for (int r4 = 0; r4 < 4; r4++){
            float rg = sigmoidf_(ar[c][r4]);
            float zg = sigmoidf_(az[c][r4]);
            float ng = tanhf_(fmaf(rg, ahn[c][r4], ain[c][r4]));
            hreg[c][r4] = fmaf(zg, hreg[c][r4] - ng, ng);
        }
    }
}

__device__ __forceinline__ void write_h(char* __restrict__ dst,
                                        const f32x4 (&hreg)[2], int w4, int lane)
{
    #pragma unroll
    for (int c = 0; c < 2; c++){
        uint32_t p0 = pkbf(hreg[c][0], hreg[c][1]);
        uint32_t p1 = pkbf(hreg[c][2], hreg[c][3]);
        int byte = (c * 16 + (lane & 15)) * 128 + w4 * 32 + (lane >> 4) * 8;
        *(uint2*)(dst + swz(byte)) = make_uint2(p0, p1);
    }
}

__global__ __launch_bounds__(256, 2)
void gru_kernel(const uint32_t* __restrict__ ebf,
                const int* __restrict__ lookup,
                const float* __restrict__ w_ih0, const float* __restrict__ w_hh0,
                const float* __restrict__ b_ih0, const float* __restrict__ b_hh0,
                const float* __restrict__ w_ih1, const float* __restrict__ w_hh1,
                const float* __restrict__ b_ih1, const float* __restrict__ b_hh1,
                const float* __restrict__ other_pos, const float* __restrict__ user_pos,
                const float* __restrict__ item_pos,
                uint32_t* __restrict__ abf,
                const int* __restrict__ adj_row, const int* __restrict__ adj_col,
                const float* __restrict__ adj_vals, int* __restrict__ cursor,
                int2* __restrict__ cv)
{
    // ---- fused scat: blocks >= GRUB scatter edges into CSR (independent of GRU) ----
    if (blockIdx.x >= GRUB){
        int e = (blockIdx.x - GRUB) * 256 + threadIdx.x;
        if (e < NEDGE){
            int p = atomicAdd(&cursor[adj_row[e]], 1);
            cv[p] = make_int2(adj_col[e], __float_as_int(adj_vals[e]));
        }
        return;   // uniform per block; exits before any __syncthreads
    }

    __shared__ __align__(16) char xbuf[2][4096];   // [32 nodes][128B bf16], swz
    __shared__ __align__(16) char h0buf[2][4096];
    __shared__ __align__(16) char h1buf[2][4096];

    const int tid  = threadIdx.x;
    const int lane = tid & 63;
    const int w4   = tid >> 6;          // wave = gate group 0..3

    const float* mats[4] = { w_ih0, w_hh0, w_ih1, w_hh1 };
    bf16x8 wf[4][3][2];
    #pragma unroll
    for (int m = 0; m < 4; m++){
        #pragma unroll
        for (int g = 0; g < 3; g++){
            #pragma unroll
            for (int kf = 0; kf < 2; kf++){
                int row = (g * 4 + w4) * 16 + (lane & 15);
                int k0  = kf * 32 + (lane >> 4) * 8;
                const float* p = mats[m] + row * 64 + k0;
                float4 a = *(const float4*)p;
                float4 b = *(const float4*)(p + 4);
                bf16x8 f;
                f[0] = (short)f2bf_rne(a.x); f[1] = (short)f2bf_rne(a.y);
                f[2] = (short)f2bf_rne(a.z); f[3] = (short)f2bf_rne(a.w);
                f[4] = (short)f2bf_rne(b.x); f[5] = (short)f2bf_rne(b.y);
                f[6] = (short)f2bf_rne(b.z); f[7] = (short)f2bf_rne(b.w);
                wf[m][g][kf] = f;
            }
        }
    }

    const int bofs = w4 * 16 + (lane >> 4) * 4;
    f32x4 rb0, zb0, ib0, hb0, rb1, zb1, ib1, hb1;
    #pragma unroll
    for (int r4 = 0; r4 < 4; r4++){
        rb0[r4] = b_ih0[bofs + r4]       + b_hh0[bofs + r4];
        zb0[r4] = b_ih0[64 + bofs + r4]  + b_hh0[64 + bofs + r4];
        ib0[r4] = b_ih0[128 + bofs + r4];
        hb0[r4] = b_hh0[128 + bofs + r4];
        rb1[r4] = b_ih1[bofs + r4]       + b_hh1[bofs + r4];
        zb1[r4] = b_ih1[64 + bofs + r4]  + b_hh1[64 + bofs + r4];
        ib1[r4] = b_ih1[128 + bofs + r4];
        hb1[r4] = b_hh1[128 + bofs + r4];
    }

    {
        uint4 z4 = make_uint4(0, 0, 0, 0);
        ((uint4*)h0buf[0])[tid] = z4;
        ((uint4*)h1buf[0])[tid] = z4;
    }
    const int pnl = tid >> 3, pdg = tid & 7;   // 8 threads stage one node's 128B row
    const long nodeP = (long)blockIdx.x * 32 + pnl;
    const int sbyte = pnl * 128 + pdg * 16;
    {
        int idx = lookup[nodeP * TSEQ + 0];
        uint4 a = ((const uint4*)(ebf + (size_t)idx * 32))[pdg];
        *(uint4*)(xbuf[0] + swz(sbyte)) = a;
    }
    __syncthreads();

    f32x4 h0reg[2], h1reg[2];
    #pragma unroll
    for (int c = 0; c < 2; c++){
        #pragma unroll
        for (int r4 = 0; r4 < 4; r4++){ h0reg[c][r4] = 0.f; h1reg[c][r4] = 0.f; }
    }

    for (int t = 0; t < TSEQ; t++){
        const int p = t & 1, q = p ^ 1;
        const bool pf = (t + 1 < TSEQ);
        uint4 xa;
        if (pf){
            int idx = lookup[nodeP * TSEQ + t + 1];
            xa = ((const uint4*)(ebf + (size_t)idx * 32))[pdg];
        }
        gru_layer_step(xbuf[p], h0buf[p], wf[0], wf[1], rb0, zb0, ib0, hb0, h0reg, lane);
        write_h(h0buf[q], h0reg, w4, lane);
        __syncthreads();
        gru_layer_step(h0buf[q], h1buf[p], wf[2], wf[3], rb1, zb1, ib1, hb1, h1reg, lane);
        write_h(h1buf[q], h1reg, w4, lane);
        if (pf) *(uint4*)(xbuf[q] + swz(sbyte)) = xa;
        __syncthreads();
    }

    // epilogue: stage fp32 h1 (32 nodes x 256B = 8KB across xbuf)
    float* xstage = (float*)xbuf;
    #pragma unroll
    for (int c = 0; c < 2; c++){
        int nl = c * 16 + (lane & 15);
        int byte = nl * 256 + w4 * 64 + (lane >> 4) * 16;
        *(float4*)((char*)xstage + swzE(byte)) =
            make_float4(h1reg[c][0], h1reg[c][1], h1reg[c][2], h1reg[c][3]);
    }
    __syncthreads();
    {
        long node = nodeP;
        const float* pp; long off;
        if (node < NBO)            { pp = other_pos; off = node; }
        else if (node < NBO + NBU) { pp = user_pos;  off = node - NBO; }
        else                       { pp = item_pos;  off = node - NBO - NBU; }
        const float* pr = pp + off * 64 + pdg * 8;
        float4 pa = *(const float4*)pr;
        float4 pb = *(const float4*)(pr + 4);
        int byte = pnl * 256 + pdg * 32;
        float4 ha = *(float4*)((char*)xstage + swzE(byte));
        float4 hb2 = *(float4*)((char*)xstage + swzE(byte + 16));
        uint4 ov;
        ov.x = pkbf(pa.x + ha.x, pa.y + ha.y);
        ov.y = pkbf(pa.z + ha.z, pa.w + ha.w);
        ov.z = pkbf(pb.x + hb2.x, pb.y + hb2.y);
        ov.w = pkbf(pb.z + hb2.z, pb.w + hb2.w);
        ((uint4*)abf)[node * 8 + pdg] = ov;
    }
}

// ---------------- prep: emb2bf (blocks [0,EB_BLKS)) + deg atomics (rest) ----------------
__global__ __launch_bounds__(256)
void prep_kernel(const float* __restrict__ we, uint32_t* __restrict__ ebf,
                 const int* __restrict__ row, int* __restrict__ deg)
{
    if (blockIdx.x < EB_BLKS){
        size_t i = (size_t)blockIdx.x * 256 + threadIdx.x;
        if (i < (size_t)EB_ELEM){
            float2 v = ((const float2*)we)[i];
            ebf[i] = pkbf(v.x, v.y);
        }
    } else {
        int e = (blockIdx.x - EB_BLKS) * 256 + threadIdx.x;
        if (e < NEDGE) atomicAdd(&deg[row[e]], 1);
    }
}

// ---------------- CSR build ----------------
__global__ __launch_bounds__(1024)
void scan1_kernel(const int* __restrict__ deg, int* __restrict__ rowptr, int* __restrict__ bsum)
{
    __shared__ int wsum[16];
    const int tid = threadIdx.x, lane = tid & 63, w = tid >> 6;
    const int i = blockIdx.x * 1024 + tid;
    int v = (i < NNODES) ? deg[i] : 0;
    int s = v;
    #pragma unroll
    for (int o = 1; o < 64; o <<= 1){
        int t = __shfl_up(s, o, 64);
        if (lane >= o) s += t;
    }
    if (lane == 63) wsum[w] = s;
    __syncthreads();
    if (w == 0){
        int t = (lane < 16) ? wsum[lane] : 0;
        #pragma unroll
        for (int o = 1; o < 16; o <<= 1){
            int u = __shfl_up(t, o, 64);
            if (lane >= o) t += u;
        }
        if (lane < 16) wsum[lane] = t;
    }
    __syncthreads();
    int incl = s + ((w > 0) ? wsum[w - 1] : 0);
    if (i < NNODES) rowptr[i + 1] = incl;
    if (tid == 0) bsum[blockIdx.x] = wsum[15];
}

// scan3 with inline block-offset reduce (replaces scan2)
__global__ __launch_bounds__(1024)
void scan3_kernel(const int* __restrict__ deg, int* __restrict__ rowptr,
                  const int* __restrict__ bsum, int* __restrict__ cursor)
{
    __shared__ int boff_sh;
    const int tid = threadIdx.x;
    if (tid < 64){
        int v = 0;
        for (int k = tid; k < blockIdx.x; k += 64) v += bsum[k];
        #pragma unroll
        for (int o = 32; o > 0; o >>= 1) v += __shfl_down(v, o, 64);
        if (tid == 0) boff_sh = v;
    }
    __syncthreads();
    const int i = blockIdx.x * 1024 + tid;
    if (i < NNODES){
        int r = rowptr[i + 1] + boff_sh;
        rowptr[i + 1] = r;
        cursor[i] = r - deg[i];
    }
    if (i == 0) rowptr[0] = 0;
}

// ---------------- CSR spmm64: one wave per row, high TLP, writes bf16 y1 ----------------
__global__ __launch_bounds__(256)
void spmm64_csr(const int* __restrict__ rowptr, const int2* __restrict__ cv,
                const ushort* __restrict__ xb, ushort* __restrict__ y1bf)
{
    const int r = blockIdx.x * 4 + (threadIdx.x >> 6);
    const int lane = threadIdx.x & 63;
    const int e0 = rowptr[r], e1 = rowptr[r + 1];
    float acc = 0.f;
    int e = e0;
    for (; e + 7 < e1; e += 8){
        int2 a[8];
        #pragma unroll
        for (int q = 0; q < 8; q++) a[q] = cv[e + q];
        float x[8];
        #pragma unroll
        for (int q = 0; q < 8; q++)
            x[q] = __uint_as_float((uint32_t)xb[(size_t)a[q].x * 64 + lane] << 16);
        #pragma unroll
        for (int q = 0; q < 8; q++) acc = fmaf(__int_as_float(a[q].y), x[q], acc);
    }
    for (; e + 3 < e1; e += 4){
        int2 a0 = cv[e], a1 = cv[e + 1], a2 = cv[e + 2], a3 = cv[e + 3];
        float x0 = __uint_as_float((uint32_t)xb[(size_t)a0.x * 64 + lane] << 16);
        float x1 = __uint_as_float((uint32_t)xb[(size_t)a1.x * 64 + lane] << 16);
        float x2 = __uint_as_float((uint32_t)xb[(size_t)a2.x * 64 + lane] << 16);
        float x3 = __uint_as_float((uint32_t)xb[(size_t)a3.x * 64 + lane] << 16);
        acc = fmaf(__int_as_float(a0.y), x0, acc);
        acc = fmaf(__int_as_float(a1.y), x1, acc);
        acc = fmaf(__int_as_float(a2.y), x2, acc);
        acc = fmaf(__int_as_float(a3.y), x3, acc);
    }
    for (; e < e1; e++){
        int2 a = cv[e];
        acc = fmaf(__int_as_float(a.y),
                   __uint_as_float((uint32_t)xb[(size_t)a.x * 64 + lane] << 16), acc);
    }
    y1bf[(size_t)r * 64 + lane] = (ushort)f2bf_rne(acc);
}

// h2c[slot] = bias + sum_e A[node(slot),c] * z2[c]  -- only 6144 scored slots
__global__ __launch_bounds__(256)
void spmm128_slots(const int* __restrict__ rowptr, const int2* __restrict__ cv,
                   const uint32_t* __restrict__ zb, const float* __restrict__ b2,
                   const int* __restrict__ user, const int* __restrict__ pos_item,
                   const int* __restrict__ neg_item, float* __restrict__ h2c)
{
    const int slot = blockIdx.x * 4 + (threadIdx.x >> 6);
    const int lane = threadIdx.x & 63;
    int r;
    if (slot < BSZ)            r = NBO + user[slot];
    else if (slot < 2 * BSZ)   r = NBO + NBU + pos_item[slot - BSZ];
    else                       r = NBO + NBU + neg_item[slot - 2 * BSZ];
    const int e0 = rowptr[r], e1 = rowptr[r + 1];
    float2 acc = make_float2(b2[2 * lane], b2[2 * lane + 1]);
    int e = e0;
    for (; e + 1 < e1; e += 2){
        int2 a0 = cv[e], a1 = cv[e + 1];
        uint32_t z0 = zb[(size_t)a0.x * 64 + lane];
        uint32_t z1 = zb[(size_t)a1.x * 64 + lane];
        float v0 = __int_as_float(a0.y), v1 = __int_as_float(a1.y);
        acc.x = fmaf(v0, bfu_lo(z0), acc.x);
        acc.y = fmaf(v0, bfu_hi(z0), acc.y);
        acc.x = fmaf(v1, bfu_lo(z1), acc.x);
        acc.y = fmaf(v1, bfu_hi(z1), acc.y);
    }
    if (e < e1){
        int2 a = cv[e];
        uint32_t z0 = zb[(size_t)a.x * 64 + lane];
        float v = __int_as_float(a.y);
        acc.x = fmaf(v, bfu_lo(z0), acc.x);
        acc.y = fmaf(v, bfu_hi(z0), acc.y);
    }
    *(float2*)(h2c + (size_t)slot * 128 + 2 * lane) = acc;
}

// ---- fused dense: h1 = y1@W1+b1 (write bf16), z2 = h1@W2 (write bf16) ----
__global__ __launch_bounds__(256, 2)
void gemm12_mfma(const uint32_t* __restrict__ y1bf,
                 const float* __restrict__ W1, const float* __restrict__ b1,
                 const float* __restrict__ W2,
                 uint32_t* __restrict__ h1bf, uint32_t* __restrict__ zbf)
{
    __shared__ __align__(16) char ybuf[8192];    // [64 nodes][128B bf16], swz
    __shared__ __align__(16) char hbuf[16384];   // [64 nodes][256B bf16], swzE
    const int tid = threadIdx.x, lane = tid & 63, w4 = tid >> 6;

    bf16x8 af1[2][2], af2[2][4];
    #pragma unroll
    for (int jt = 0; jt < 2; jt++){
        int jj = w4 * 32 + jt * 16 + (lane & 15);
        #pragma unroll
        for (int kf = 0; kf < 2; kf++){
            int k0 = kf * 32 + (lane >> 4) * 8;
            bf16x8 f;
            #pragma unroll
            for (int i = 0; i < 8; i++) f[i] = (short)f2bf_rne(W1[(size_t)(k0 + i) * 128 + jj]);
            af1[jt][kf] = f;
        }
        #pragma unroll
        for (int kf = 0; kf < 4; kf++){
            int k0 = kf * 32 + (lane >> 4) * 8;
            bf16x8 f;
            #pragma unroll
            for (int i = 0; i < 8; i++) f[i] = (short)f2bf_rne(W2[(size_t)(k0 + i) * 128 + jj]);
            af2[jt][kf] = f;
        }
    }
    float b1v[2][4];
    #pragma unroll
    for (int jt = 0; jt < 2; jt++)
        #pragma unroll
        for (int r4 = 0; r4 < 4; r4++)
            b1v[jt][r4] = b1[w4 * 32 + jt * 16 + (lane >> 4) * 4 + r4];

    // stage y1 tile (already bf16): 4 threads/node, 32B each
    const int snl = tid >> 2, sq = tid & 3;
    {
        const uint32_t* yr = y1bf + ((size_t)blockIdx.x * 64 + snl) * 32 + sq * 8;
        uint4 p0 = *(const uint4*)yr;
        uint4 p1 = *(const uint4*)(yr + 4);
        int base = snl * 128 + sq * 32;
        *(uint4*)(ybuf + swz(base))      = p0;
        *(uint4*)(ybuf + swz(base + 16)) = p1;
    }
    __syncthreads();

    // pass 1: h1 = y1 @ W1 + b1
    f32x4 acc[2][4];
    #pragma unroll
    for (int jt = 0; jt < 2; jt++)
        #pragma unroll
        for (int ct = 0; ct < 4; ct++)
            #pragma unroll
            for (int r4 = 0; r4 < 4; r4++) acc[jt][ct][r4] = b1v[jt][r4];
    {
        const int lrow = (lane & 15) * 128 + (lane >> 4) * 16;
        __builtin_amdgcn_s_setprio(1);
        #pragma unroll
        for (int kf = 0; kf < 2; kf++){
            #pragma unroll
            for (int ct = 0; ct < 4; ct++){
                int byte = ct * 2048 + kf * 64 + lrow;
                bf16x8 bfr = *(const bf16x8*)(ybuf + swz(byte));
                acc[0][ct] = mfma16(af1[0][kf], bfr, acc[0][ct]);
                acc[1][ct] = mfma16(af1[1][kf], bfr, acc[1][ct]);
            }
        }
        __builtin_amdgcn_s_setprio(0);
    }
    // stage h1 bf16 into hbuf [node][256B] swzE
    #pragma unroll
    for (int jt = 0; jt < 2; jt++){
        #pragma unroll
        for (int ct = 0; ct < 4; ct++){
            int node = ct * 16 + (lane & 15);
            int j2 = (w4 * 32 + jt * 16 + (lane >> 4) * 4) >> 1;
            uint32_t p0 = pkbf(acc[jt][ct][0], acc[jt][ct][1]);
            uint32_t p1 = pkbf(acc[jt][ct][2], acc[jt][ct][3]);
            *(uint2*)(hbuf + swzE(node * 256 + j2 * 4)) = make_uint2(p0, p1);
        }
    }
    __syncthreads();

    // global h1 write (coalesced) + pass 2 MFMA reads (both read hbuf)
    {
        uint32_t* dst = h1bf + ((size_t)blockIdx.x * 64 + snl) * 64 + sq * 16;
        #pragma unroll
        for (int q = 0; q < 4; q++)
            *(uint4*)(dst + q * 4) = *(uint4*)(hbuf + swzE(snl * 256 + sq * 64 + q * 16));
    }
    f32x4 acc2[2][4];
    #pragma unroll
    for (int jt = 0; jt < 2; jt++)
        #pragma unroll
        for (int ct = 0; ct < 4; ct++)
            #pragma unroll
            for (int r4 = 0; r4 < 4; r4++) acc2[jt][ct][r4] = 0.f;
    {
        const int lrow = (lane & 15) * 256 + (lane >> 4) * 16;
        __builtin_amdgcn_s_setprio(1);
        #pragma unroll
        for (int kf = 0; kf < 4; kf++){
            #pragma unroll
            for (int ct = 0; ct < 4; ct++){
                int byte = ct * 4096 + kf * 64 + lrow;
                bf16x8 bfr = *(const bf16x8*)(hbuf + swzE(byte));
                acc2[0][ct] = mfma16(af2[0][kf], bfr, acc2[0][ct]);
                acc2[1][ct] = mfma16(af2[1][kf], bfr, acc2[1][ct]);
            }
        }
        __builtin_amdgcn_s_setprio(0);
    }
    __syncthreads();   // all hbuf reads done before z-stage overwrites

    #pragma unroll
    for (int jt = 0; jt < 2; jt++){
        #pragma unroll
        for (int ct = 0; ct < 4; ct++){
            int node = ct * 16 + (lane & 15);
            int j2 = (w4 * 32 + jt * 16 + (lane >> 4) * 4) >> 1;
            uint32_t p0 = pkbf(acc2[jt][ct][0], acc2[jt][ct][1]);
            uint32_t p1 = pkbf(acc2[jt][ct][2], acc2[jt][ct][3]);
            *(uint2*)(hbuf + swzE(node * 256 + j2 * 4)) = make_uint2(p0, p1);
        }
    }
    __syncthreads();
    {
        uint32_t* dst = zbf + ((size_t)blockIdx.x * 64 + snl) * 64 + sq * 16;
        #pragma unroll
        for (int q = 0; q < 4; q++)
            *(uint4*)(dst + q * 4) = *(uint4*)(hbuf + swzE(snl * 256 + sq * 64 + q * 16));
    }
}

// ---------------- merged scoring: one block per b handles user/pos/4 negs ----------------
__global__ __launch_bounds__(128)
void score_kernel(const uint32_t* __restrict__ h1bf, const float* __restrict__ h2c,
                  const float* __restrict__ lin_w, const float* __restrict__ lin_b,
                  const int* __restrict__ user, const int* __restrict__ pos_item,
                  const int* __restrict__ neg_item, float* __restrict__ bloss)
{
    const int b = blockIdx.x, j = threadIdx.x;
    const int un = NBO + user[b];
    const int pn = NBO + NBU + pos_item[b];
    const int n0 = NBO + NBU + neg_item[b];
    const int n1 = NBO + NBU + neg_item[BSZ + b];
    const int n2 = NBO + NBU + neg_item[2 * BSZ + b];
    const int n3 = NBO + NBU + neg_item[3 * BSZ + b];
    const float* lw = lin_w + j * 256;
    const uint32_t* h1u = h1bf + (size_t)un * 64;  const float* h2u = h2c + (size_t)b * 128;
    const uint32_t* h1p = h1bf + (size_t)pn * 64;  const float* h2p = h2c + (size_t)(BSZ + b) * 128;
    const uint32_t* h1a = h1bf + (size_t)n0 * 64;  const float* h2a = h2c + (size_t)(2 * BSZ + b) * 128;
    const uint32_t* h1b = h1bf + (size_t)n1 * 64;  const float* h2b = h2c + (size_t)(3 * BSZ + b) * 128;
    const uint32_t* h1c = h1bf + (size_t)n2 * 64;  const float* h2cc = h2c + (size_t)(4 * BSZ + b) * 128;
    const uint32_t* h1d = h1bf + (size_t)n3 * 64;  const float* h2d = h2c + (size_t)(5 * BSZ + b) * 128;
    float lb = lin_b[j];
    float ua = lb, pa = lb, a0 = lb, a1 = lb, a2 = lb, a3 = lb;
    #pragma unroll 4
    for (int m2 = 0; m2 < 64; m2++){
        float w1l = lw[2 * m2], w1h = lw[2 * m2 + 1];
        uint32_t wu = h1u[m2], wp = h1p[m2], wa = h1a[m2], wb = h1b[m2], wc = h1c[m2], wd = h1d[m2];
        ua = fmaf(bfu_lo(wu), w1l, ua); ua = fmaf(bfu_hi(wu), w1h, ua);
        pa = fmaf(bfu_lo(wp), w1l, pa); pa = fmaf(bfu_hi(wp), w1h, pa);
        a0 = fmaf(bfu_lo(wa), w1l, a0); a0 = fmaf(bfu_hi(wa), w1h, a0);
        a1 = fmaf(bfu_lo(wb), w1l, a1); a1 = fmaf(bfu_hi(wb), w1h, a1);
        a2 = fmaf(bfu_lo(wc), w1l, a2); a2 = fmaf(bfu_hi(wc), w1h, a2);
        a3 = fmaf(bfu_lo(wd), w1l, a3); a3 = fmaf(bfu_hi(wd), w1h, a3);
    }
    #pragma unroll 4
    for (int m = 0; m < 128; m++){
        float w2 = lw[128 + m];
        ua = fmaf(h2u[m], w2, ua);
        pa = fmaf(h2p[m], w2, pa);
        a0 = fmaf(h2a[m], w2, a0);
        a1 = fmaf(h2b[m], w2, a1);
        a2 = fmaf(h2cc[m], w2, a2);
        a3 = fmaf(h2d[m], w2, a3);
    }
    float dp = ua * pa;
    float dn = ua * (a0 + a1 + a2 + a3);
    #pragma unroll
    for (int off = 32; off > 0; off >>= 1){
        dp += __shfl_down(dp, off, 64);
        dn += __shfl_down(dn, off, 64);
    }
    __shared__ float red[4];
    if ((j & 63) == 0){ red[(j >> 6) * 2] = dp; red[(j >> 6) * 2 + 1] = dn; }
    __syncthreads();
    if (j == 0){
        float P = red[0] + red[2];
        float N = red[1] + red[3];
        float v = 0.25f * N - P + 1.0f;
        bloss[b] = fminf(fmaxf(v, 1e-6f), 1e4f);
    }
}

__global__ __launch_bounds__(1024)
void loss_kernel(const float* __restrict__ bloss, float* __restrict__ out)
{
    const int t = threadIdx.x;
    float v = bloss[t];
    #pragma unroll
    for (int off = 32; off > 0; off >>= 1) v += __shfl_down(v, off, 64);
    __shared__ float red[16];
    if ((t & 63) == 0) red[t >> 6] = v;
    __syncthreads();
    if (t == 0){
        float s = 0.f;
        #pragma unroll
        for (int i = 0; i < 16; i++) s += red[i];
        out[0] = s;
    }
}

extern "C" void kernel_launch(void* const* d_in, const int* in_sizes, int n_in,
                              void* d_out, int out_size, void* d_ws, size_t ws_size,
                              hipStream_t stream)
{
    const float* word_emb  = (const float*)d_in[0];
    const float* other_pos = (const float*)d_in[1];
    const float* user_pos  = (const float*)d_in[2];
    const float* item_pos  = (const float*)d_in[3];
    const float* w_ih0 = (const float*)d_in[4];
    const float* w_hh0 = (const float*)d_in[5];
    const float* b_ih0 = (const float*)d_in[6];
    const float* b_hh0 = (const float*)d_in[7];
    const float* w_ih1 = (const float*)d_in[8];
    const float* w_hh1 = (const float*)d_in[9];
    const float* b_ih1 = (const float*)d_in[10];
    const float* b_hh1 = (const float*)d_in[11];
    const float* conv1_w = (const float*)d_in[12];
    const float* conv1_b = (const float*)d_in[13];
    const float* conv2_w = (const float*)d_in[14];
    const float* conv2_b = (const float*)d_in[15];
    const float* lin_w   = (const float*)d_in[16];
    const float* lin_b   = (const float*)d_in[17];
    const int* adj_row = (const int*)d_in[18];
    const int* adj_col = (const int*)d_in[19];
    const float* adj_vals = (const float*)d_in[20];
    const int* lookup   = (const int*)d_in[21];
    const int* user     = (const int*)d_in[22];
    const int* pos_item = (const int*)d_in[23];
    const int* neg_item = (const int*)d_in[24];

    float* ws = (float*)d_ws;

    uint32_t* h1bf = (uint32_t*)ws;                        // [N*64]  4,608,000 w
    uint32_t* zbf  = h1bf + 4608000;                       // [N*64]  4,608,000 w
    float*    h2c  = (float*)(zbf + 4608000);              // [NSLOT*128] 786,432 w
    uint32_t* abf  = (uint32_t*)(h2c + 786432);            // [N*32]  2,304,000 w
    uint32_t* ebf  = abf + 2304000;                        // [(V+1)*32] 1,600,032 w
    uint32_t* y1bf = ebf + 1600032;                        // [N*32]  2,304,000 w (packed bf16)
    float*    bloss = (float*)(y1bf + 2304000);            // [1024]
    int* rowptr = (int*)(bloss + 1088);                    // [NNODES+1]
    int* cursor = rowptr + 72004;
    int* deg    = cursor + 72004;
    int* bsum   = deg + 72004;                             // [NSB]
    int2* cv    = (int2*)(bsum + 128);                     // [NEDGE]

    (void)hipMemsetAsync(deg, 0, NNODES * sizeof(int), stream);

    prep_kernel<<<EB_BLKS + DEG_BLKS, 256, 0, stream>>>(word_emb, ebf, adj_row, deg);

    scan1_kernel<<<NSB, 1024, 0, stream>>>(deg, rowptr, bsum);
    scan3_kernel<<<NSB, 1024, 0, stream>>>(deg, rowptr, bsum, cursor);

    // fused: blocks [0,GRUB) = GRU, blocks [GRUB, GRUB+SCAT_BLKS) = CSR scatter
    gru_kernel<<<GRUB + SCAT_BLKS, 256, 0, stream>>>(
        ebf, lookup, w_ih0, w_hh0, b_ih0, b_hh0,
        w_ih1, w_hh1, b_ih1, b_hh1,
        other_pos, user_pos, item_pos, abf,
        adj_row, adj_col, adj_vals, cursor, cv);

    spmm64_csr<<<NNODES / 4, 256, 0, stream>>>(rowptr, cv, (const ushort*)abf, (ushort*)y1bf);

    gemm12_mfma<<<NNODES / 64, 256, 0, stream>>>(y1bf, conv1_w, conv1_b, conv2_w, h1bf, zbf);

    spmm128_slots<<<NSLOT / 4, 256, 0, stream>>>(rowptr, cv, zbf, conv2_b,
                                                 user, pos_item, neg_item, h2c);

    score_kernel<<<BSZ, 128, 0, stream>>>(h1bf, h2c, lin_w, lin_b, user, pos_item, neg_item, bloss);

    loss_kernel<<<1, 1024, 0, stream>>>(bloss, (float*)d_out);
}

// Round 17
// 414.101 us; speedup vs baseline: 1.4239x; 1.0094x over previous
//
#include <hip/hip_runtime.h>
#include <hip/hip_bf16.h>
#include <stdint.h>

#define NNODES 72000
#define NBO 2000
#define NBU 20000
#define NBI 50000
#define NEDGE 1152000
#define VOCAB 50000
#define TSEQ 20
#define BSZ 1024
#define KNEG 4
#define NSB 71     // scan blocks: 71*1024 >= 72000
#define EB_ELEM ((VOCAB + 1) * 32)     // 1,600,032 packed words
#define EB_BLKS ((EB_ELEM + 255) / 256)
#define DEG_BLKS ((NEDGE + 255) / 256)
#define GRUB (NNODES / 32)             // 2250 gru blocks
#define SCAT_BLKS ((NEDGE + 255) / 256)

typedef __attribute__((ext_vector_type(8))) short bf16x8;
typedef __attribute__((ext_vector_type(4))) float f32x4;

__device__ __forceinline__ float rcp_fast(float x){ return __builtin_amdgcn_rcpf(x); }
__device__ __forceinline__ float sigmoidf_(float x){ return rcp_fast(1.f + __expf(-x)); }
__device__ __forceinline__ float tanhf_(float x){
    float xx = fminf(fmaxf(x, -15.f), 15.f);
    float e = __expf(-2.f * xx);
    return (1.f - e) * rcp_fast(1.f + e);
}
__device__ __forceinline__ uint32_t f2bf_rne(float f){
    uint32_t u = __float_as_uint(f);
    return (u + 0x7fffu + ((u >> 16) & 1u)) >> 16;
}
// HW packed convert: 2 fp32 -> 2 bf16 (v_cvt_pk_bf16_f32); memcpy = reg move
__device__ __forceinline__ uint32_t pkbf(float lo, float hi){
    __hip_bfloat162 h = __float22bfloat162_rn(make_float2(lo, hi));
    uint32_t r;
    __builtin_memcpy(&r, &h, 4);
    return r;
}
__device__ __forceinline__ float bfu_lo(uint32_t p){ return __uint_as_float(p << 16); }
__device__ __forceinline__ float bfu_hi(uint32_t p){ return __uint_as_float(p & 0xffff0000u); }

__device__ __forceinline__ f32x4 mfma16(bf16x8 a, bf16x8 b, f32x4 c){
    return __builtin_amdgcn_mfma_f32_16x16x32_bf16(a, b, c, 0, 0, 0);
}

// XOR swizzle for 128B-row LDS tiles (16B slots spread per 8-row stripe)
__device__ __forceinline__ int swz(int b){ return b ^ (((b >> 7) & 7) << 4); }
// XOR swizzle for 256B-row tiles
__device__ __forceinline__ int swzE(int b){ return b ^ (((b >> 8) & 7) << 4); }

// ---------------- MFMA GRU (r15 proven) + fused scat tail blocks ----------------

__device__ __forceinline__ void gru_layer_step(
    const char* __restrict__ xsrc, const char* __restrict__ hsrc,
    const bf16x8 (&wih)[3][2], const bf16x8 (&whh)[3][2],
    const f32x4& rb, const f32x4& zb, const f32x4& ib, const f32x4& hb,
    f32x4 (&hreg)[2], int lane)
{
    f32x4 ar[2], az[2], ain[2], ahn[2];
    #pragma unroll
    for (int c = 0; c < 2; c++){ ar[c] = rb; az[c] = zb; ain[c] = ib; ahn[c] = hb; }
    const int lrow = (lane & 15) * 128 + (lane >> 4) * 16;
    __builtin_amdgcn_s_setprio(1);
    #pragma unroll
    for (int kf = 0; kf < 2; kf++){
        #pragma unroll
        for (int c = 0; c < 2; c++){
            int byte = c * 2048 + kf * 64 + lrow;
            bf16x8 bx = *(const bf16x8*)(xsrc + swz(byte));
            bf16x8 bh = *(const bf16x8*)(hsrc + swz(byte));
            ar[c]  = mfma16(wih[0][kf], bx, ar[c]);
            ar[c]  = mfma16(whh[0][kf], bh, ar[c]);
            az[c]  = mfma16(wih[1][kf], bx, az[c]);
            az[c]  = mfma16(whh[1][kf], bh, az[c]);
            ain[c] = mfma16(wih[2][kf], bx, ain[c]);
            ahn[c] = mfma16(whh[2][kf], bh, ahn[c]);
        }
    }
    __builtin_amdgcn_s_setprio(0);
    #pragma unroll
    for (int c = 0; c < 2; c++){
        #pragma unroll
        for (int r4 = 0; r4 < 4; r4++){
            float rg = sigmoidf_(ar[c][r4]);
            float zg = sigmoidf_(az[c][r4]);
            float ng = tanhf_(fmaf(rg, ahn[c][r4], ain[c][r4]));
            hreg[c][r4] = fmaf(zg, hreg[c][r4] - ng, ng);
        }
    }
}

__device__ __forceinline__ void write_h(char* __restrict__ dst,
                                        const f32x4 (&hreg)[2], int w4, int lane)
{
    #pragma unroll
    for (int c = 0; c < 2; c++){
        uint32_t p0 = pkbf(hreg[c][0], hreg[c][1]);
        uint32_t p1 = pkbf(hreg[c][2], hreg[c][3]);
        int byte = (c * 16 + (lane & 15)) * 128 + w4 * 32 + (lane >> 4) * 8;
        *(uint2*)(dst + swz(byte)) = make_uint2(p0, p1);
    }
}

__global__ __launch_bounds__(256, 2)
void gru_kernel(const uint32_t* __restrict__ ebf,
                const int* __restrict__ lookup,
                const float* __restrict__ w_ih0, const float* __restrict__ w_hh0,
                const float* __restrict__ b_ih0, const float* __restrict__ b_hh0,
                const float* __restrict__ w_ih1, const float* __restrict__ w_hh1,
                const float* __restrict__ b_ih1, const float* __restrict__ b_hh1,
                const float* __restrict__ other_pos, const float* __restrict__ user_pos,
                const float* __restrict__ item_pos,
                uint32_t* __restrict__ abf,
                const int* __restrict__ adj_row, const int* __restrict__ adj_col,
                const float* __restrict__ adj_vals, int* __restrict__ cursor,
                int2* __restrict__ cv)
{
    // ---- fused scat: blocks >= GRUB scatter edges into CSR (independent of GRU) ----
    if (blockIdx.x >= GRUB){
        int e = (blockIdx.x - GRUB) * 256 + threadIdx.x;
        if (e < NEDGE){
            int p = atomicAdd(&cursor[adj_row[e]], 1);
            cv[p] = make_int2(adj_col[e], __float_as_int(adj_vals[e]));
        }
        return;   // uniform per block; exits before any __syncthreads
    }

    __shared__ __align__(16) char xbuf[2][4096];   // [32 nodes][128B bf16], swz
    __shared__ __align__(16) char h0buf[2][4096];
    __shared__ __align__(16) char h1buf[2][4096];

    const int tid  = threadIdx.x;
    const int lane = tid & 63;
    const int w4   = tid >> 6;          // wave = gate group 0..3

    const float* mats[4] = { w_ih0, w_hh0, w_ih1, w_hh1 };
    bf16x8 wf[4][3][2];
    #pragma unroll
    for (int m = 0; m < 4; m++){
        #pragma unroll
        for (int g = 0; g < 3; g++){
            #pragma unroll
            for (int kf = 0; kf < 2; kf++){
                int row = (g * 4 + w4) * 16 + (lane & 15);
                int k0  = kf * 32 + (lane >> 4) * 8;
                const float* p = mats[m] + row * 64 + k0;
                float4 a = *(const float4*)p;
                float4 b = *(const float4*)(p + 4);
                bf16x8 f;
                f[0] = (short)f2bf_rne(a.x); f[1] = (short)f2bf_rne(a.y);
                f[2] = (short)f2bf_rne(a.z); f[3] = (short)f2bf_rne(a.w);
                f[4] = (short)f2bf_rne(b.x); f[5] = (short)f2bf_rne(b.y);
                f[6] = (short)f2bf_rne(b.z); f[7] = (short)f2bf_rne(b.w);
                wf[m][g][kf] = f;
            }
        }
    }

    const int bofs = w4 * 16 + (lane >> 4) * 4;
    f32x4 rb0, zb0, ib0, hb0, rb1, zb1, ib1, hb1;
    #pragma unroll
    for (int r4 = 0; r4 < 4; r4++){
        rb0[r4] = b_ih0[bofs + r4]       + b_hh0[bofs + r4];
        zb0[r4] = b_ih0[64 + bofs + r4]  + b_hh0[64 + bofs + r4];
        ib0[r4] = b_ih0[128 + bofs + r4];
        hb0[r4] = b_hh0[128 + bofs + r4];
        rb1[r4] = b_ih1[bofs + r4]       + b_hh1[bofs + r4];
        zb1[r4] = b_ih1[64 + bofs + r4]  + b_hh1[64 + bofs + r4];
        ib1[r4] = b_ih1[128 + bofs + r4];
        hb1[r4] = b_hh1[128 + bofs + r4];
    }

    {
        uint4 z4 = make_uint4(0, 0, 0, 0);
        ((uint4*)h0buf[0])[tid] = z4;
        ((uint4*)h1buf[0])[tid] = z4;
    }
    const int pnl = tid >> 3, pdg = tid & 7;   // 8 threads stage one node's 128B row
    const long nodeP = (long)blockIdx.x * 32 + pnl;
    const int sbyte = pnl * 128 + pdg * 16;
    {
        int idx = lookup[nodeP * TSEQ + 0];
        uint4 a = ((const uint4*)(ebf + (size_t)idx * 32))[pdg];
        *(uint4*)(xbuf[0] + swz(sbyte)) = a;
    }
    __syncthreads();

    f32x4 h0reg[2], h1reg[2];
    #pragma unroll
    for (int c = 0; c < 2; c++){
        #pragma unroll
        for (int r4 = 0; r4 < 4; r4++){ h0reg[c][r4] = 0.f; h1reg[c][r4] = 0.f; }
    }

    for (int t = 0; t < TSEQ; t++){
        const int p = t & 1, q = p ^ 1;
        const bool pf = (t + 1 < TSEQ);
        uint4 xa;
        if (pf){
            int idx = lookup[nodeP * TSEQ + t + 1];
            xa = ((const uint4*)(ebf + (size_t)idx * 32))[pdg];
        }
        gru_layer_step(xbuf[p], h0buf[p], wf[0], wf[1], rb0, zb0, ib0, hb0, h0reg, lane);
        write_h(h0buf[q], h0reg, w4, lane);
        __syncthreads();
        gru_layer_step(h0buf[q], h1buf[p], wf[2], wf[3], rb1, zb1, ib1, hb1, h1reg, lane);
        write_h(h1buf[q], h1reg, w4, lane);
        if (pf) *(uint4*)(xbuf[q] + swz(sbyte)) = xa;
        __syncthreads();
    }

    // epilogue: stage fp32 h1 (32 nodes x 256B = 8KB across xbuf)
    float* xstage = (float*)xbuf;
    #pragma unroll
    for (int c = 0; c < 2; c++){
        int nl = c * 16 + (lane & 15);
        int byte = nl * 256 + w4 * 64 + (lane >> 4) * 16;
        *(float4*)((char*)xstage + swzE(byte)) =
            make_float4(h1reg[c][0], h1reg[c][1], h1reg[c][2], h1reg[c][3]);
    }
    __syncthreads();
    {
        long node = nodeP;
        const float* pp; long off;
        if (node < NBO)            { pp = other_pos; off = node; }
        else if (node < NBO + NBU) { pp = user_pos;  off = node - NBO; }
        else                       { pp = item_pos;  off = node - NBO - NBU; }
        const float* pr = pp + off * 64 + pdg * 8;
        float4 pa = *(const float4*)pr;
        float4 pb = *(const float4*)(pr + 4);
        int byte = pnl * 256 + pdg * 32;
        float4 ha = *(float4*)((char*)xstage + swzE(byte));
        float4 hb2 = *(float4*)((char*)xstage + swzE(byte + 16));
        uint4 ov;
        ov.x = pkbf(pa.x + ha.x, pa.y + ha.y);
        ov.y = pkbf(pa.z + ha.z, pa.w + ha.w);
        ov.z = pkbf(pb.x + hb2.x, pb.y + hb2.y);
        ov.w = pkbf(pb.z + hb2.z, pb.w + hb2.w);
        ((uint4*)abf)[node * 8 + pdg] = ov;
    }
}

// ---------------- prep: emb2bf (blocks [0,EB_BLKS)) + deg atomics (rest) ----------------
__global__ __launch_bounds__(256)
void prep_kernel(const float* __restrict__ we, uint32_t* __restrict__ ebf,
                 const int* __restrict__ row, int* __restrict__ deg)
{
    if (blockIdx.x < EB_BLKS){
        size_t i = (size_t)blockIdx.x * 256 + threadIdx.x;
        if (i < (size_t)EB_ELEM){
            float2 v = ((const float2*)we)[i];
            ebf[i] = pkbf(v.x, v.y);
        }
    } else {
        int e = (blockIdx.x - EB_BLKS) * 256 + threadIdx.x;
        if (e < NEDGE) atomicAdd(&deg[row[e]], 1);
    }
}

// ---------------- CSR build ----------------
__global__ __launch_bounds__(1024)
void scan1_kernel(const int* __restrict__ deg, int* __restrict__ rowptr, int* __restrict__ bsum)
{
    __shared__ int wsum[16];
    const int tid = threadIdx.x, lane = tid & 63, w = tid >> 6;
    const int i = blockIdx.x * 1024 + tid;
    int v = (i < NNODES) ? deg[i] : 0;
    int s = v;
    #pragma unroll
    for (int o = 1; o < 64; o <<= 1){
        int t = __shfl_up(s, o, 64);
        if (lane >= o) s += t;
    }
    if (lane == 63) wsum[w] = s;
    __syncthreads();
    if (w == 0){
        int t = (lane < 16) ? wsum[lane] : 0;
        #pragma unroll
        for (int o = 1; o < 16; o <<= 1){
            int u = __shfl_up(t, o, 64);
            if (lane >= o) t += u;
        }
        if (lane < 16) wsum[lane] = t;
    }
    __syncthreads();
    int incl = s + ((w > 0) ? wsum[w - 1] : 0);
    if (i < NNODES) rowptr[i + 1] = incl;
    if (tid == 0) bsum[blockIdx.x] = wsum[15];
}

// scan3 with inline block-offset reduce (replaces scan2)
__global__ __launch_bounds__(1024)
void scan3_kernel(const int* __restrict__ deg, int* __restrict__ rowptr,
                  const int* __restrict__ bsum, int* __restrict__ cursor)
{
    __shared__ int boff_sh;
    const int tid = threadIdx.x;
    if (tid < 64){
        int v = 0;
        for (int k = tid; k < blockIdx.x; k += 64) v += bsum[k];
        #pragma unroll
        for (int o = 32; o > 0; o >>= 1) v += __shfl_down(v, o, 64);
        if (tid == 0) boff_sh = v;
    }
    __syncthreads();
    const int i = blockIdx.x * 1024 + tid;
    if (i < NNODES){
        int r = rowptr[i + 1] + boff_sh;
        rowptr[i + 1] = r;
        cursor[i] = r - deg[i];
    }
    if (i == 0) rowptr[0] = 0;
}

// ---------------- CSR spmm64: one wave per row, high TLP, writes bf16 y1 ----------------
__global__ __launch_bounds__(256)
void spmm64_csr(const int* __restrict__ rowptr, const int2* __restrict__ cv,
                const ushort* __restrict__ xb, ushort* __restrict__ y1bf)
{
    const int r = blockIdx.x * 4 + (threadIdx.x >> 6);
    const int lane = threadIdx.x & 63;
    const int e0 = rowptr[r], e1 = rowptr[r + 1];
    float acc = 0.f;
    int e = e0;
    for (; e + 7 < e1; e += 8){
        int2 a[8];
        #pragma unroll
        for (int q = 0; q < 8; q++) a[q] = cv[e + q];
        float x[8];
        #pragma unroll
        for (int q = 0; q < 8; q++)
            x[q] = __uint_as_float((uint32_t)xb[(size_t)a[q].x * 64 + lane] << 16);
        #pragma unroll
        for (int q = 0; q < 8; q++) acc = fmaf(__int_as_float(a[q].y), x[q], acc);
    }
    for (; e + 3 < e1; e += 4){
        int2 a0 = cv[e], a1 = cv[e + 1], a2 = cv[e + 2], a3 = cv[e + 3];
        float x0 = __uint_as_float((uint32_t)xb[(size_t)a0.x * 64 + lane] << 16);
        float x1 = __uint_as_float((uint32_t)xb[(size_t)a1.x * 64 + lane] << 16);
        float x2 = __uint_as_float((uint32_t)xb[(size_t)a2.x * 64 + lane] << 16);
        float x3 = __uint_as_float((uint32_t)xb[(size_t)a3.x * 64 + lane] << 16);
        acc = fmaf(__int_as_float(a0.y), x0, acc);
        acc = fmaf(__int_as_float(a1.y), x1, acc);
        acc = fmaf(__int_as_float(a2.y), x2, acc);
        acc = fmaf(__int_as_float(a3.y), x3, acc);
    }
    for (; e < e1; e++){
        int2 a = cv[e];
        acc = fmaf(__int_as_float(a.y),
                   __uint_as_float((uint32_t)xb[(size_t)a.x * 64 + lane] << 16), acc);
    }
    y1bf[(size_t)r * 64 + lane] = (ushort)f2bf_rne(acc);
}

// ---- fused dense: h1 = y1@W1+b1 (write bf16), z2 = h1@W2 (write bf16) ----
__global__ __launch_bounds__(256, 2)
void gemm12_mfma(const uint32_t* __restrict__ y1bf,
                 const float* __restrict__ W1, const float* __restrict__ b1,
                 const float* __restrict__ W2,
                 uint32_t* __restrict__ h1bf, uint32_t* __restrict__ zbf)
{
    __shared__ __align__(16) char ybuf[8192];    // [64 nodes][128B bf16], swz
    __shared__ __align__(16) char hbuf[16384];   // [64 nodes][256B bf16], swzE
    const int tid = threadIdx.x, lane = tid & 63, w4 = tid >> 6;

    bf16x8 af1[2][2], af2[2][4];
    #pragma unroll
    for (int jt = 0; jt < 2; jt++){
        int jj = w4 * 32 + jt * 16 + (lane & 15);
        #pragma unroll
        for (int kf = 0; kf < 2; kf++){
            int k0 = kf * 32 + (lane >> 4) * 8;
            bf16x8 f;
            #pragma unroll
            for (int i = 0; i < 8; i++) f[i] = (short)f2bf_rne(W1[(size_t)(k0 + i) * 128 + jj]);
            af1[jt][kf] = f;
        }
        #pragma unroll
        for (int kf = 0; kf < 4; kf++){
            int k0 = kf * 32 + (lane >> 4) * 8;
            bf16x8 f;
            #pragma unroll
            for (int i = 0; i < 8; i++) f[i] = (short)f2bf_rne(W2[(size_t)(k0 + i) * 128 + jj]);
            af2[jt][kf] = f;
        }
    }
    float b1v[2][4];
    #pragma unroll
    for (int jt = 0; jt < 2; jt++)
        #pragma unroll
        for (int r4 = 0; r4 < 4; r4++)
            b1v[jt][r4] = b1[w4 * 32 + jt * 16 + (lane >> 4) * 4 + r4];

    // stage y1 tile (already bf16): 4 threads/node, 32B each
    const int snl = tid >> 2, sq = tid & 3;
    {
        const uint32_t* yr = y1bf + ((size_t)blockIdx.x * 64 + snl) * 32 + sq * 8;
        uint4 p0 = *(const uint4*)yr;
        uint4 p1 = *(const uint4*)(yr + 4);
        int base = snl * 128 + sq * 32;
        *(uint4*)(ybuf + swz(base))      = p0;
        *(uint4*)(ybuf + swz(base + 16)) = p1;
    }
    __syncthreads();

    // pass 1: h1 = y1 @ W1 + b1
    f32x4 acc[2][4];
    #pragma unroll
    for (int jt = 0; jt < 2; jt++)
        #pragma unroll
        for (int ct = 0; ct < 4; ct++)
            #pragma unroll
            for (int r4 = 0; r4 < 4; r4++) acc[jt][ct][r4] = b1v[jt][r4];
    {
        const int lrow = (lane & 15) * 128 + (lane >> 4) * 16;
        __builtin_amdgcn_s_setprio(1);
        #pragma unroll
        for (int kf = 0; kf < 2; kf++){
            #pragma unroll
            for (int ct = 0; ct < 4; ct++){
                int byte = ct * 2048 + kf * 64 + lrow;
                bf16x8 bfr = *(const bf16x8*)(ybuf + swz(byte));
                acc[0][ct] = mfma16(af1[0][kf], bfr, acc[0][ct]);
                acc[1][ct] = mfma16(af1[1][kf], bfr, acc[1][ct]);
            }
        }
        __builtin_amdgcn_s_setprio(0);
    }
    // stage h1 bf16 into hbuf [node][256B] swzE
    #pragma unroll
    for (int jt = 0; jt < 2; jt++){
        #pragma unroll
        for (int ct = 0; ct < 4; ct++){
            int node = ct * 16 + (lane & 15);
            int j2 = (w4 * 32 + jt * 16 + (lane >> 4) * 4) >> 1;
            uint32_t p0 = pkbf(acc[jt][ct][0], acc[jt][ct][1]);
            uint32_t p1 = pkbf(acc[jt][ct][2], acc[jt][ct][3]);
            *(uint2*)(hbuf + swzE(node * 256 + j2 * 4)) = make_uint2(p0, p1);
        }
    }
    __syncthreads();

    // global h1 write (coalesced) + pass 2 MFMA reads (both read hbuf)
    {
        uint32_t* dst = h1bf + ((size_t)blockIdx.x * 64 + snl) * 64 + sq * 16;
        #pragma unroll
        for (int q = 0; q < 4; q++)
            *(uint4*)(dst + q * 4) = *(uint4*)(hbuf + swzE(snl * 256 + sq * 64 + q * 16));
    }
    f32x4 acc2[2][4];
    #pragma unroll
    for (int jt = 0; jt < 2; jt++)
        #pragma unroll
        for (int ct = 0; ct < 4; ct++)
            #pragma unroll
            for (int r4 = 0; r4 < 4; r4++) acc2[jt][ct][r4] = 0.f;
    {
        const int lrow = (lane & 15) * 256 + (lane >> 4) * 16;
        __builtin_amdgcn_s_setprio(1);
        #pragma unroll
        for (int kf = 0; kf < 4; kf++){
            #pragma unroll
            for (int ct = 0; ct < 4; ct++){
                int byte = ct * 4096 + kf * 64 + lrow;
                bf16x8 bfr = *(const bf16x8*)(hbuf + swzE(byte));
                acc2[0][ct] = mfma16(af2[0][kf], bfr, acc2[0][ct]);
                acc2[1][ct] = mfma16(af2[1][kf], bfr, acc2[1][ct]);
            }
        }
        __builtin_amdgcn_s_setprio(0);
    }
    __syncthreads();   // all hbuf reads done before z-stage overwrites

    #pragma unroll
    for (int jt = 0; jt < 2; jt++){
        #pragma unroll
        for (int ct = 0; ct < 4; ct++){
            int node = ct * 16 + (lane & 15);
            int j2 = (w4 * 32 + jt * 16 + (lane >> 4) * 4) >> 1;
            uint32_t p0 = pkbf(acc2[jt][ct][0], acc2[jt][ct][1]);
            uint32_t p1 = pkbf(acc2[jt][ct][2], acc2[jt][ct][3]);
            *(uint2*)(hbuf + swzE(node * 256 + j2 * 4)) = make_uint2(p0, p1);
        }
    }
    __syncthreads();
    {
        uint32_t* dst = zbf + ((size_t)blockIdx.x * 64 + snl) * 64 + sq * 16;
        #pragma unroll
        for (int q = 0; q < 4; q++)
            *(uint4*)(dst + q * 4) = *(uint4*)(hbuf + swzE(snl * 256 + sq * 64 + q * 16));
    }
}

// ---------------- fused scoring: inline spmm128 for the 6 slots + dots ----------------
__global__ __launch_bounds__(128)
void score_kernel(const int* __restrict__ rowptr, const int2* __restrict__ cv,
                  const uint32_t* __restrict__ zb, const float* __restrict__ b2,
                  const uint32_t* __restrict__ h1bf,
                  const float* __restrict__ lin_w, const float* __restrict__ lin_b,
                  const int* __restrict__ user, const int* __restrict__ pos_item,
                  const int* __restrict__ neg_item, float* __restrict__ bloss)
{
    __shared__ float h2s[6][128];
    const int b = blockIdx.x, j = threadIdx.x;
    int nodes[6];
    nodes[0] = NBO + user[b];
    nodes[1] = NBO + NBU + pos_item[b];
    nodes[2] = NBO + NBU + neg_item[b];
    nodes[3] = NBO + NBU + neg_item[BSZ + b];
    nodes[4] = NBO + NBU + neg_item[2 * BSZ + b];
    nodes[5] = NBO + NBU + neg_item[3 * BSZ + b];

    // inline spmm128: h2s[s][j] = b2[j] + sum_e v_e * z2[col_e][j]
    const int w2i = j >> 1;            // packed word index (dims 2w,2w+1)
    const bool hi = j & 1;
    const float bias2 = b2[j];
    #pragma unroll
    for (int s = 0; s < 6; s++){
        const int r = nodes[s];
        const int e0 = rowptr[r], e1 = rowptr[r + 1];
        float acc = bias2;
        int e = e0;
        for (; e + 1 < e1; e += 2){
            int2 a0 = cv[e], a1 = cv[e + 1];
            uint32_t z0 = zb[(size_t)a0.x * 64 + w2i];
            uint32_t z1 = zb[(size_t)a1.x * 64 + w2i];
            acc = fmaf(__int_as_float(a0.y), hi ? bfu_hi(z0) : bfu_lo(z0), acc);
            acc = fmaf(__int_as_float(a1.y), hi ? bfu_hi(z1) : bfu_lo(z1), acc);
        }
        if (e < e1){
            int2 a = cv[e];
            uint32_t z0 = zb[(size_t)a.x * 64 + w2i];
            acc = fmaf(__int_as_float(a.y), hi ? bfu_hi(z0) : bfu_lo(z0), acc);
        }
        h2s[s][j] = acc;
    }
    __syncthreads();

    const float* lw = lin_w + j * 256;
    const uint32_t* h1u = h1bf + (size_t)nodes[0] * 64;
    const uint32_t* h1p = h1bf + (size_t)nodes[1] * 64;
    const uint32_t* h1a = h1bf + (size_t)nodes[2] * 64;
    const uint32_t* h1b = h1bf + (size_t)nodes[3] * 64;
    const uint32_t* h1c = h1bf + (size_t)nodes[4] * 64;
    const uint32_t* h1d = h1bf + (size_t)nodes[5] * 64;
    float lb = lin_b[j];
    float ua = lb, pa = lb, a0 = lb, a1 = lb, a2 = lb, a3 = lb;
    #pragma unroll 4
    for (int m2 = 0; m2 < 64; m2++){
        float w1l = lw[2 * m2], w1h = lw[2 * m2 + 1];
        uint32_t wu = h1u[m2], wp = h1p[m2], wa = h1a[m2], wb = h1b[m2], wc = h1c[m2], wd = h1d[m2];
        ua = fmaf(bfu_lo(wu), w1l, ua); ua = fmaf(bfu_hi(wu), w1h, ua);
        pa = fmaf(bfu_lo(wp), w1l, pa); pa = fmaf(bfu_hi(wp), w1h, pa);
        a0 = fmaf(bfu_lo(wa), w1l, a0); a0 = fmaf(bfu_hi(wa), w1h, a0);
        a1 = fmaf(bfu_lo(wb), w1l, a1); a1 = fmaf(bfu_hi(wb), w1h, a1);
        a2 = fmaf(bfu_lo(wc), w1l, a2); a2 = fmaf(bfu_hi(wc), w1h, a2);
        a3 = fmaf(bfu_lo(wd), w1l, a3); a3 = fmaf(bfu_hi(wd), w1h, a3);
    }
    #pragma unroll 4
    for (int m = 0; m < 128; m++){
        float w2 = lw[128 + m];
        ua = fmaf(h2s[0][m], w2, ua);
        pa = fmaf(h2s[1][m], w2, pa);
        a0 = fmaf(h2s[2][m], w2, a0);
        a1 = fmaf(h2s[3][m], w2, a1);
        a2 = fmaf(h2s[4][m], w2, a2);
        a3 = fmaf(h2s[5][m], w2, a3);
    }
    float dp = ua * pa;
    float dn = ua * (a0 + a1 + a2 + a3);
    #pragma unroll
    for (int off = 32; off > 0; off >>= 1){
        dp += __shfl_down(dp, off, 64);
        dn += __shfl_down(dn, off, 64);
    }
    __shared__ float red[4];
    if ((j & 63) == 0){ red[(j >> 6) * 2] = dp; red[(j >> 6) * 2 + 1] = dn; }
    __syncthreads();
    if (j == 0){
        float P = red[0] + red[2];
        float N = red[1] + red[3];
        float v = 0.25f * N - P + 1.0f;
        bloss[b] = fminf(fmaxf(v, 1e-6f), 1e4f);
    }
}

__global__ __launch_bounds__(1024)
void loss_kernel(const float* __restrict__ bloss, float* __restrict__ out)
{
    const int t = threadIdx.x;
    float v = bloss[t];
    #pragma unroll
    for (int off = 32; off > 0; off >>= 1) v += __shfl_down(v, off, 64);
    __shared__ float red[16];
    if ((t & 63) == 0) red[t >> 6] = v;
    __syncthreads();
    if (t == 0){
        float s = 0.f;
        #pragma unroll
        for (int i = 0; i < 16; i++) s += red[i];
        out[0] = s;
    }
}

extern "C" void kernel_launch(void* const* d_in, const int* in_sizes, int n_in,
                              void* d_out, int out_size, void* d_ws, size_t ws_size,
                              hipStream_t stream)
{
    const float* word_emb  = (const float*)d_in[0];
    const float* other_pos = (const float*)d_in[1];
    const float* user_pos  = (const float*)d_in[2];
    const float* item_pos  = (const float*)d_in[3];
    const float* w_ih0 = (const float*)d_in[4];
    const float* w_hh0 = (const float*)d_in[5];
    const float* b_ih0 = (const float*)d_in[6];
    const float* b_hh0 = (const float*)d_in[7];
    const float* w_ih1 = (const float*)d_in[8];
    const float* w_hh1 = (const float*)d_in[9];
    const float* b_ih1 = (const float*)d_in[10];
    const float* b_hh1 = (const float*)d_in[11];
    const float* conv1_w = (const float*)d_in[12];
    const float* conv1_b = (const float*)d_in[13];
    const float* conv2_w = (const float*)d_in[14];
    const float* conv2_b = (const float*)d_in[15];
    const float* lin_w   = (const float*)d_in[16];
    const float* lin_b   = (const float*)d_in[17];
    const int* adj_row = (const int*)d_in[18];
    const int* adj_col = (const int*)d_in[19];
    const float* adj_vals = (const float*)d_in[20];
    const int* lookup   = (const int*)d_in[21];
    const int* user     = (const int*)d_in[22];
    const int* pos_item = (const int*)d_in[23];
    const int* neg_item = (const int*)d_in[24];

    float* ws = (float*)d_ws;

    uint32_t* h1bf = (uint32_t*)ws;                        // [N*64]  4,608,000 w
    uint32_t* zbf  = h1bf + 4608000;                       // [N*64]  4,608,000 w
    uint32_t* abf  = zbf + 4608000;                        // [N*32]  2,304,000 w
    uint32_t* ebf  = abf + 2304000;                        // [(V+1)*32] 1,600,032 w
    uint32_t* y1bf = ebf + 1600032;                        // [N*32]  2,304,000 w (packed bf16)
    float*    bloss = (float*)(y1bf + 2304000);            // [1024]
    int* rowptr = (int*)(bloss + 1088);                    // [NNODES+1]
    int* cursor = rowptr + 72004;
    int* deg    = cursor + 72004;
    int* bsum   = deg + 72004;                             // [NSB]
    int2* cv    = (int2*)(bsum + 128);                     // [NEDGE]

    (void)hipMemsetAsync(deg, 0, NNODES * sizeof(int), stream);

    prep_kernel<<<EB_BLKS + DEG_BLKS, 256, 0, stream>>>(word_emb, ebf, adj_row, deg);

    scan1_kernel<<<NSB, 1024, 0, stream>>>(deg, rowptr, bsum);
    scan3_kernel<<<NSB, 1024, 0, stream>>>(deg, rowptr, bsum, cursor);

    // fused: blocks [0,GRUB) = GRU, blocks [GRUB, GRUB+SCAT_BLKS) = CSR scatter
    gru_kernel<<<GRUB + SCAT_BLKS, 256, 0, stream>>>(
        ebf, lookup, w_ih0, w_hh0, b_ih0, b_hh0,
        w_ih1, w_hh1, b_ih1, b_hh1,
        other_pos, user_pos, item_pos, abf,
        adj_row, adj_col, adj_vals, cursor, cv);

    spmm64_csr<<<NNODES / 4, 256, 0, stream>>>(rowptr, cv, (const ushort*)abf, (ushort*)y1bf);

    gemm12_mfma<<<NNODES / 64, 256, 0, stream>>>(y1bf, conv1_w, conv1_b, conv2_w, h1bf, zbf);

    score_kernel<<<BSZ, 128, 0, stream>>>(rowptr, cv, zbf, conv2_b, h1bf,
                                          lin_w, lin_b, user, pos_item, neg_item, bloss);

    loss_kernel<<<1, 1024, 0, stream>>>(bloss, (float*)d_out);
}